// Round 11
// baseline (384.508 us; speedup 1.0000x reference)
//
#include <hip/hip_runtime.h>
#include <hip/hip_bf16.h>

#define B_ 2
#define T_ 1024
#define C_ 1024
#define H_ 16

typedef short bf16x8 __attribute__((ext_vector_type(8)));
typedef float f32x4 __attribute__((ext_vector_type(4)));

#define MFMA16(a, b, c) __builtin_amdgcn_mfma_f32_16x16x32_bf16(a, b, c, 0, 0, 0)

__device__ inline short f2bf(float x) {
    union { __hip_bfloat16 h; short s; } u;
    u.h = __float2bfloat16(x);
    return u.s;
}

__device__ inline void gl_lds16(const void* g, void* l) {
    __builtin_amdgcn_global_load_lds(
        (const __attribute__((address_space(1))) unsigned int*)g,
        (__attribute__((address_space(3))) unsigned int*)l, 16, 0, 0);
}

// ---------------------------------------------------------------------------
// Kernel: x (fp32) -> xb (bf16), flat. 2M elems, 8/thread.
// ---------------------------------------------------------------------------
__global__ __launch_bounds__(256) void cvt_x(const float* __restrict__ x,
                                             short* __restrict__ xb) {
    int idx = (blockIdx.x * 256 + threadIdx.x) * 8;
    float4 a = *(const float4*)(x + idx);
    float4 b = *(const float4*)(x + idx + 4);
    bf16x8 v;
    v[0] = f2bf(a.x); v[1] = f2bf(a.y); v[2] = f2bf(a.z); v[3] = f2bf(a.w);
    v[4] = f2bf(b.x); v[5] = f2bf(b.y); v[6] = f2bf(b.z); v[7] = f2bf(b.w);
    *(bf16x8*)(xb + idx) = v;
}

// ---------------------------------------------------------------------------
// Kernel: generic fp32->bf16 64x64 tile transpose.
//   dst[(g*1024 + r)*1024 + c] = bf16(src[(g*1024 + c)*1024 + r])
// Used for Wt (g = h, grid 4096) AND xbT (g = b, grid 512).
// ---------------------------------------------------------------------------
__global__ __launch_bounds__(256) void cvt_w(const float* __restrict__ W,
                                             short* __restrict__ Wt) {
    __shared__ float T[64][65];
    const int bid = blockIdx.x;
    const int nb = bid & 15, cb = (bid >> 4) & 15, h = bid >> 8;
    const int t = threadIdx.x;
    const int c0 = cb * 64, n0 = nb * 64;
    const float* src = W + (size_t)(h * 1024 + c0) * 1024 + n0;
    {
        const int cl = t >> 4, nl = (t & 15) * 4;
#pragma unroll
        for (int r = 0; r < 4; ++r) {
            float4 v = *(const float4*)(src + (size_t)(cl + r * 16) * 1024 + nl);
            T[cl + r * 16][nl + 0] = v.x;
            T[cl + r * 16][nl + 1] = v.y;
            T[cl + r * 16][nl + 2] = v.z;
            T[cl + r * 16][nl + 3] = v.w;
        }
    }
    __syncthreads();
    {
        short* dst = Wt + (size_t)(h * 1024 + n0) * 1024 + c0;
        const int nl = t >> 3, cl8 = (t & 7) * 8;
#pragma unroll
        for (int r = 0; r < 2; ++r) {
            const int n = nl + r * 32;
            bf16x8 o;
#pragma unroll
            for (int j = 0; j < 8; ++j) o[j] = f2bf(T[cl8 + j][n]);
            *(bf16x8*)(dst + (size_t)n * 1024 + cl8) = o;
        }
    }
}

// ---------------------------------------------------------------------------
// Kernel: attn_po v3 (round-6/8/9/10 proven, ~155 us). UNCHANGED.
// ---------------------------------------------------------------------------
__global__ __launch_bounds__(512, 2) void attn_po(const short* __restrict__ xb,
                                                  const short* __restrict__ xbT,
                                                  short* __restrict__ O) {
    __shared__ short Pb[2][64][72];     // probs bf16, double-buffered
    __shared__ float row_al[2][64];
    __shared__ float row_l[64];
    __shared__ int   flags[2][4];

    const int tid = threadIdx.x;
    const int bh = blockIdx.x & 31;                  // XCD-pinned (b,h)
    const int rest = blockIdx.x >> 5;                // 0..15
    const int tb = (rest < 8) ? rest : 23 - rest;    // pair long+short tiles
    const int b = bh >> 4, h = bh & 15;
    const int lane = tid & 63, q = lane >> 4, l16 = lane & 15;
    const int w = tid >> 6;
    const int g = w & 3;          // QK row-group
    const int nw = w * 128;       // PV channel base
    const short* xbb = xb + ((size_t)b << 20);
    const short* vtb = xbT + ((size_t)b << 20);   // [c][s], s contiguous

    const int t0 = tb * 64;
    const int nch = tb + 1;

    f32x4 acc[4][8];
#pragma unroll
    for (int mt = 0; mt < 4; ++mt)
#pragma unroll
        for (int nt = 0; nt < 8; ++nt) acc[mt][nt] = (f32x4){0.f, 0.f, 0.f, 0.f};
    float m_r[4], l_r[4];
#pragma unroll
    for (int r = 0; r < 4; ++r) { m_r[r] = -3.0e38f; l_r[r] = 0.f; }

    bf16x8 qf[2];
    if (w < 4) {
#pragma unroll
        for (int ks = 0; ks < 2; ++ks)
            qf[ks] = *(const bf16x8*)(xbb + (size_t)(t0 + g * 16 + l16) * 1024 +
                                      h * 64 + ks * 32 + q * 8);
    }

    for (int ci = -1; ci < nch; ++ci) {
        __syncthreads();
        const int cc = ci + 1;
        if (w < 4 && cc < nch) {
            const int s0 = (cc == 0) ? t0 : (cc - 1) * 64;
            const int par = cc & 1;
            // QK^T
            f32x4 sf[4];
#pragma unroll
            for (int st = 0; st < 4; ++st) sf[st] = (f32x4){0.f, 0.f, 0.f, 0.f};
#pragma unroll
            for (int st = 0; st < 4; ++st)
#pragma unroll
                for (int ks = 0; ks < 2; ++ks) {
                    bf16x8 kf = *(const bf16x8*)(xbb +
                        (size_t)(s0 + st * 16 + l16) * 1024 + h * 64 + ks * 32 + q * 8);
                    sf[st] = MFMA16(qf[ks], kf, sf[st]);
                }
            // In-register online softmax (rows q*4+r of group g)
            float mx[4] = {-3.0e38f, -3.0e38f, -3.0e38f, -3.0e38f};
#pragma unroll
            for (int st = 0; st < 4; ++st)
#pragma unroll
                for (int r = 0; r < 4; ++r) {
                    float v = sf[st][r] * 0.25f;
                    if (cc == 0 && (s0 + st * 16 + l16) > (t0 + g * 16 + q * 4 + r))
                        v = -3.0e38f;
                    sf[st][r] = v;
                    mx[r] = fmaxf(mx[r], v);
                }
#pragma unroll
            for (int r = 0; r < 4; ++r) {
                mx[r] = fmaxf(mx[r], __shfl_xor(mx[r], 1));
                mx[r] = fmaxf(mx[r], __shfl_xor(mx[r], 2));
                mx[r] = fmaxf(mx[r], __shfl_xor(mx[r], 4));
                mx[r] = fmaxf(mx[r], __shfl_xor(mx[r], 8));
            }
            float sum[4], al[4];
            int upd = 0;
#pragma unroll
            for (int r = 0; r < 4; ++r) {
                float m_new = fmaxf(m_r[r], mx[r]);
                al[r] = __expf(m_r[r] - m_new);
                upd |= (m_new > m_r[r]) ? 1 : 0;
                m_r[r] = m_new;
                sum[r] = 0.f;
            }
#pragma unroll
            for (int st = 0; st < 4; ++st)
#pragma unroll
                for (int r = 0; r < 4; ++r) {
                    float pv = __expf(sf[st][r] - m_r[r]);
                    sum[r] += pv;
                    Pb[par][g * 16 + q * 4 + r][st * 16 + l16] = f2bf(pv);
                }
#pragma unroll
            for (int r = 0; r < 4; ++r) {
                sum[r] += __shfl_xor(sum[r], 1);
                sum[r] += __shfl_xor(sum[r], 2);
                sum[r] += __shfl_xor(sum[r], 4);
                sum[r] += __shfl_xor(sum[r], 8);
                l_r[r] = l_r[r] * al[r] + sum[r];
            }
            if (l16 == 0) {
#pragma unroll
                for (int r = 0; r < 4; ++r) row_al[par][g * 16 + q * 4 + r] = al[r];
            }
            int any_upd = __any(upd);
            if (lane == 0) flags[par][g] = any_upd;
        }
        if (ci >= 0) {
            const int par = ci & 1;
            // Rescale accumulators only if some row max moved.
            if (flags[par][0] | flags[par][1] | flags[par][2] | flags[par][3]) {
#pragma unroll
                for (int mt = 0; mt < 4; ++mt) {
                    float a0 = row_al[par][mt * 16 + q * 4 + 0];
                    float a1 = row_al[par][mt * 16 + q * 4 + 1];
                    float a2 = row_al[par][mt * 16 + q * 4 + 2];
                    float a3 = row_al[par][mt * 16 + q * 4 + 3];
#pragma unroll
                    for (int nt = 0; nt < 8; ++nt) {
                        acc[mt][nt][0] *= a0;
                        acc[mt][nt][1] *= a1;
                        acc[mt][nt][2] *= a2;
                        acc[mt][nt][3] *= a3;
                    }
                }
            }
            // PV: V-fragments from xbT (L2-hot), point-of-use.
            bf16x8 pf[4][2];
#pragma unroll
            for (int mt = 0; mt < 4; ++mt)
#pragma unroll
                for (int ks = 0; ks < 2; ++ks)
                    pf[mt][ks] = *(bf16x8*)&Pb[par][mt * 16 + l16][ks * 32 + q * 8];
            const int s0p = (ci == 0) ? t0 : (ci - 1) * 64;
#pragma unroll
            for (int nt = 0; nt < 8; ++nt)
#pragma unroll
                for (int ks = 0; ks < 2; ++ks) {
                    bf16x8 vf = *(const bf16x8*)(vtb +
                        (size_t)(nw + nt * 16 + l16) * 1024 + s0p + ks * 32 + q * 8);
#pragma unroll
                    for (int mt = 0; mt < 4; ++mt)
                        acc[mt][nt] = MFMA16(pf[mt][ks], vf, acc[mt][nt]);
                }
        }
    }

    // Epilogue: share row sums, normalize, PLAIN bf16 stores to O.
    if (w < 4 && l16 == 0) {
#pragma unroll
        for (int r = 0; r < 4; ++r) row_l[g * 16 + q * 4 + r] = l_r[r];
    }
    __syncthreads();
    short* ob = O + ((((size_t)(b * 1024 + t0) * 16) + h) << 10);
#pragma unroll
    for (int mt = 0; mt < 4; ++mt) {
        float i0 = 1.f / row_l[mt * 16 + q * 4 + 0];
        float i1 = 1.f / row_l[mt * 16 + q * 4 + 1];
        float i2 = 1.f / row_l[mt * 16 + q * 4 + 2];
        float i3 = 1.f / row_l[mt * 16 + q * 4 + 3];
#pragma unroll
        for (int nt = 0; nt < 8; ++nt) {
            size_t base = (size_t)(mt * 16 + q * 4) * 16384 + nw + nt * 16 + l16;
            ob[base]         = f2bf(acc[mt][nt][0] * i0);
            ob[base + 16384] = f2bf(acc[mt][nt][1] * i1);
            ob[base + 32768] = f2bf(acc[mt][nt][2] * i2);
            ob[base + 49152] = f2bf(acc[mt][nt][3] * i3);
        }
    }
}

// ---------------------------------------------------------------------------
// Kernel: ogemm v7 — out[m][n] += O[m][k] * Wt[k->(h,c)][n].
// Base = v6 (159 us: split-K 4, grid 512, XCD swizzle, BK=64, FETCH 66 MB)
// + ONE change: TRUE double-buffer pipeline (T3 minimum recipe).
// Evidence: rounds 8-10 fixed locality (FETCH ideal) and falsified TLP and
// step count; 6k cy/step vs 310 cy MFMA = per-step load latency serially
// exposed, because __syncthreads() forces a vmcnt(0) drain BEFORE compute
// (m97-ceiling mechanism). New structure per phase:
//   STAGE(next tile -> OTHER buffer)  // issued first, in flight during MFMA
//   ds_read+MFMA(current buffer)
//   asm s_waitcnt vmcnt(0)            // waits AFTER compute covered latency
//   __builtin_amdgcn_s_barrier()      // raw barrier, no implicit drain
// Pair-unrolled so buffers are 4 DISTINCT __shared__ arrays with
// compile-time indices -> alias analysis can prove prefetch writes don't
// alias current reads (else compiler re-inserts the defensive drain; rule
// m99/m100 failure mode). LDS 64 KB -> 2 blocks/CU, (256,2).
// Watch: MfmaUtil -> ~25-32 if the pipeline holds; neutral if defeated.
// Epilogue: fp32 atomicAdd (out pre-zeroed), 8.4M atomics.
// ---------------------------------------------------------------------------
__global__ __launch_bounds__(256, 2) void ogemm(const short* __restrict__ O,
                                                const short* __restrict__ Wt,
                                                float* __restrict__ out) {
    __shared__ short Al0[8][128][8];   // 16 KiB  (buffer 0, A)
    __shared__ short Bl0[8][128][8];   // 16 KiB  (buffer 0, B)
    __shared__ short Al1[8][128][8];   // 16 KiB  (buffer 1, A)
    __shared__ short Bl1[8][128][8];   // 16 KiB  (buffer 1, B)

    const int orig = blockIdx.x;                   // HW: XCD = orig & 7
    const int x = orig & 7, j = orig >> 3;         // j in 0..63
    const int kq  = x >> 1;                        // 0..3 (2 XCDs per kq)
    const int m_t = (x & 1) * 8 + (j >> 3);        // 0..15
    const int n_t = j & 7;                         // 0..7 (fast: O reuse)
    const int m0 = m_t * 128, n0 = n_t * 128;
    const int t = threadIdx.x;
    const int lane = t & 63, q = lane >> 4, l16 = lane & 15;
    const int wv = t >> 6;
    const int wm = (wv & 1) * 64, wn = (wv >> 1) * 64;

    const short* Ab = O + (size_t)m0 * 16384;
    const int srow = t & 127, skg = t >> 7;        // staging row / k-group

    char* a0 = (char*)&Al0[0][0][0] + (size_t)t * 16;
    char* b0 = (char*)&Bl0[0][0][0] + (size_t)t * 16;
    char* a1 = (char*)&Al1[0][0][0] + (size_t)t * 16;
    char* b1 = (char*)&Bl1[0][0][0] + (size_t)t * 16;

    f32x4 acc[4][4];
#pragma unroll
    for (int i = 0; i < 4; ++i)
#pragma unroll
        for (int j2 = 0; j2 < 4; ++j2) acc[i][j2] = (f32x4){0.f, 0.f, 0.f, 0.f};

    const int kbase = kq * 4096;

#define OG_STAGE(K0, AB, BB)                                                   \
    {                                                                          \
        const int k0_ = (K0);                                                  \
        const int h_ = k0_ >> 10, c0_ = k0_ & 1023;                            \
        const short* Arow_ = Ab + (size_t)srow * 16384 + k0_;                  \
        const short* Brow_ = Wt + ((size_t)h_ << 20) +                         \
                             (size_t)(n0 + srow) * 1024 + c0_;                 \
        _Pragma("unroll")                                                      \
        for (int jj = 0; jj < 4; ++jj) {                                       \
            gl_lds16(Arow_ + (2 * jj + skg) * 8, (AB) + jj * 4096);            \
            gl_lds16(Brow_ + (2 * jj + skg) * 8, (BB) + jj * 4096);            \
        }                                                                      \
    }

#define OG_COMPUTE(ALARR, BLARR)                                               \
    _Pragma("unroll")                                                          \
    for (int ks = 0; ks < 2; ++ks) {                                           \
        bf16x8 af[4], bfr[4];                                                  \
        _Pragma("unroll")                                                      \
        for (int i = 0; i < 4; ++i)                                            \
            af[i] = *(bf16x8*)&ALARR[q + 4 * ks][wm + i * 16 + l16][0];        \
        _Pragma("unroll")                                                      \
        for (int j2 = 0; j2 < 4; ++j2)                                         \
            bfr[j2] = *(bf16x8*)&BLARR[q + 4 * ks][wn + j2 * 16 + l16][0];     \
        _Pragma("unroll")                                                      \
        for (int i = 0; i < 4; ++i)                                            \
            _Pragma("unroll")                                                  \
            for (int j2 = 0; j2 < 4; ++j2)                                     \
                acc[i][j2] = MFMA16(af[i], bfr[j2], acc[i][j2]);               \
    }

    // Prologue: fill buffer 0 with the first K-tile.
    OG_STAGE(kbase, a0, b0);
    asm volatile("s_waitcnt vmcnt(0)" ::: "memory");
    __builtin_amdgcn_s_barrier();

    for (int kk = 0; kk < 4096; kk += 128) {
        // Phase A: prefetch (kk+64) -> buf1, compute buf0 (kk).
        OG_STAGE(kbase + kk + 64, a1, b1);
        OG_COMPUTE(Al0, Bl0);
        asm volatile("s_waitcnt vmcnt(0)" ::: "memory");
        __builtin_amdgcn_s_barrier();

        // Phase B: prefetch (kk+128) -> buf0 (guarded), compute buf1 (kk+64).
        if (kk + 128 < 4096) OG_STAGE(kbase + kk + 128, a0, b0);
        OG_COMPUTE(Al1, Bl1);
        asm volatile("s_waitcnt vmcnt(0)" ::: "memory");
        __builtin_amdgcn_s_barrier();
    }
#undef OG_STAGE
#undef OG_COMPUTE

    // Epilogue: out[m][n] atomic add (split-K partial).
#pragma unroll
    for (int i = 0; i < 4; ++i)
#pragma unroll
        for (int j2 = 0; j2 < 4; ++j2)
#pragma unroll
            for (int r = 0; r < 4; ++r) {
                int m = m0 + wm + i * 16 + q * 4 + r;
                int n = n0 + wn + j2 * 16 + l16;
                atomicAdd(out + (size_t)m * 1024 + n, acc[i][j2][r]);
            }
}

// ---------------------------------------------------------------------------
// Fallback path kernels (round-0 proven): zgemm_fast/zgemm_sm + atomic attn.
// ---------------------------------------------------------------------------
__global__ __launch_bounds__(256, 4) void zgemm_fast(const short* __restrict__ xb,
                                                     const short* __restrict__ Wt,
                                                     short* __restrict__ ZT) {
    __shared__ short Al[4][128][8];
    __shared__ short Bl[4][128][8];

    const int bid = blockIdx.x;
    const int n_t = bid & 7, h = (bid >> 3) & 15, s_t = bid >> 7;
    const int n0 = n_t * 128, s0g = s_t * 128;
    const int t = threadIdx.x;
    const int lane = t & 63, q = lane >> 4, l16 = lane & 15;
    const int wv = t >> 6;
    const int wm = (wv & 1) * 64, wn = (wv >> 1) * 64;

    const short* Ab = Wt + ((size_t)h * 1024 + n0) * 1024;
    const short* Bb = xb + (size_t)s0g * 1024;
    const int srow = t & 127, skg = t >> 7;

    char* al_base = (char*)&Al[0][0][0] + (size_t)t * 16;
    char* bl_base = (char*)&Bl[0][0][0] + (size_t)t * 16;

    f32x4 acc[4][4];
#pragma unroll
    for (int i = 0; i < 4; ++i)
#pragma unroll
        for (int j = 0; j < 4; ++j) acc[i][j] = (f32x4){0.f, 0.f, 0.f, 0.f};

    for (int k0 = 0; k0 < 1024; k0 += 32) {
        __syncthreads();
        gl_lds16(Ab + (size_t)srow * 1024 + k0 + skg * 8, al_base);
        gl_lds16(Ab + (size_t)srow * 1024 + k0 + (skg + 2) * 8, al_base + 4096);
        gl_lds16(Bb + (size_t)srow * 1024 + k0 + skg * 8, bl_base);
        gl_lds16(Bb + (size_t)srow * 1024 + k0 + (skg + 2) * 8, bl_base + 4096);
        __syncthreads();
        bf16x8 af[4], bfr[4];
#pragma unroll
        for (int i = 0; i < 4; ++i) af[i] = *(bf16x8*)&Al[q][wm + i * 16 + l16][0];
#pragma unroll
        for (int j = 0; j < 4; ++j) bfr[j] = *(bf16x8*)&Bl[q][wn + j * 16 + l16][0];
#pragma unroll
        for (int i = 0; i < 4; ++i)
#pragma unroll
            for (int j = 0; j < 4; ++j)
                acc[i][j] = MFMA16(af[i], bfr[j], acc[i][j]);
    }

    const int b = s0g >> 10, s_in0 = s0g & 1023;
    short* zb = ZT + ((size_t)(b * 16 + h) << 20);
#pragma unroll
    for (int i = 0; i < 4; ++i)
#pragma unroll
        for (int j = 0; j < 4; ++j)
#pragma unroll
            for (int r = 0; r < 4; ++r) {
                int n = n0 + wm + i * 16 + q * 4 + r;
                int s = s_in0 + wn + j * 16 + l16;
                zb[(size_t)n * 1024 + s] = f2bf(acc[i][j][r]);
            }
}

#define ZPAD 40

__global__ __launch_bounds__(256, 2) void zgemm_sm(const short* __restrict__ xb,
                                                   const float* __restrict__ W,
                                                   short* __restrict__ ZT) {
    __shared__ short Wts[128 * ZPAD];
    __shared__ short Xs[2][128 * ZPAD];

    const int tid = threadIdx.x;
    const int bs = blockIdx.x & 7;
    const int bn = (blockIdx.x >> 3) & 7;
    const int h  = blockIdx.x >> 6;
    const int s0 = bs * 128, n0 = bn * 128;
    const int lane = tid & 63, q = lane >> 4, l16 = lane & 15;
    const int w = tid >> 6, bw = w >> 1, sh = w & 1;

    f32x4 acc[8][4];
#pragma unroll
    for (int i = 0; i < 8; ++i)
#pragma unroll
        for (int j = 0; j < 4; ++j) acc[i][j] = (f32x4){0.f, 0.f, 0.f, 0.f};

    for (int k0 = 0; k0 < 1024; k0 += 32) {
        __syncthreads();
#pragma unroll
        for (int r = 0; r < 2; ++r) {
            const int c2 = ((tid >> 5) << 1) + (r << 4);
            const float* w0p = W + (size_t)(h * 1024 + k0 + c2) * 1024 + n0;
            const float* w1p = w0p + 1024;
#pragma unroll
            for (int i = 0; i < 4; ++i) {
                const int n = (tid & 31) + (i << 5);
                float wa = w0p[n], wb = w1p[n];
                unsigned u = (unsigned)(unsigned short)f2bf(wa) |
                             ((unsigned)(unsigned short)f2bf(wb) << 16);
                *(unsigned*)&Wts[n * ZPAD + c2] = u;
            }
        }
#pragma unroll
        for (int i = 0; i < 4; ++i) {
            const int id = tid + (i << 8);
            const int b2 = id >> 9, s = (id >> 2) & 127, cg = id & 3;
            bf16x8 v = *(const bf16x8*)(xb + (size_t)b2 * (T_ * C_) +
                                        (size_t)(s0 + s) * 1024 + k0 + cg * 8);
            *(bf16x8*)&Xs[b2][s * ZPAD + cg * 8] = v;
        }
        __syncthreads();

        bf16x8 af[8], bfr[4];
#pragma unroll
        for (int nt = 0; nt < 8; ++nt)
            af[nt] = *(bf16x8*)&Wts[(nt * 16 + l16) * ZPAD + q * 8];
#pragma unroll
        for (int st = 0; st < 4; ++st)
            bfr[st] = *(bf16x8*)&Xs[bw][(sh * 64 + st * 16 + l16) * ZPAD + q * 8];
#pragma unroll
        for (int nt = 0; nt < 8; ++nt)
#pragma unroll
            for (int st = 0; st < 4; ++st)
                acc[nt][st] = MFMA16(af[nt], bfr[st], acc[nt][st]);
    }

    short* zb = ZT + (size_t)(bw * 16 + h) * (1024 * 1024);
#pragma unroll
    for (int nt = 0; nt < 8; ++nt)
#pragma unroll
        for (int st = 0; st < 4; ++st)
#pragma unroll
            for (int r = 0; r < 4; ++r) {
                int n_abs = n0 + nt * 16 + q * 4 + r;
                int s_abs = s0 + sh * 64 + st * 16 + l16;
                zb[(size_t)n_abs * 1024 + s_abs] = f2bf(acc[nt][st][r]);
            }
}

__global__ __launch_bounds__(512, 2) void attn(const short* __restrict__ xb,
                                               const short* __restrict__ ZT,
                                               float* __restrict__ out) {
    __shared__ short Pb[2][64][72];
    __shared__ float row_al[2][64];
    __shared__ float row_l[64];
    __shared__ int   flags[2][4];

    const int tid = threadIdx.x;
    const int bh = blockIdx.x & 31, p = blockIdx.x >> 5;
    const int b = bh >> 4, h = bh & 15;
    const int lane = tid & 63, q = lane >> 4, l16 = lane & 15;
    const int w = tid >> 6;
    const int g = w & 3;
    const int nw = w * 128;
    const short* xbb = xb + ((size_t)b << 20);
    const short* ztb = ZT + ((size_t)(b * 16 + h) << 20);

    const int tiles[2] = { p, 15 - p };
    for (int ti = 0; ti < 2; ++ti) {
        const int tb = tiles[ti];
        const int t0 = tb * 64;
        const int nch = tb + 1;

        f32x4 acc[4][8];
#pragma unroll
        for (int mt = 0; mt < 4; ++mt)
#pragma unroll
            for (int nt = 0; nt < 8; ++nt) acc[mt][nt] = (f32x4){0.f, 0.f, 0.f, 0.f};
        float m_r[4], l_r[4];
#pragma unroll
        for (int r = 0; r < 4; ++r) { m_r[r] = -3.0e38f; l_r[r] = 0.f; }

        bf16x8 qf[2];
        if (w < 4) {
#pragma unroll
            for (int ks = 0; ks < 2; ++ks)
                qf[ks] = *(const bf16x8*)(xbb + (size_t)(t0 + g * 16 + l16) * 1024 +
                                          h * 64 + ks * 32 + q * 8);
        }

        for (int ci = -1; ci < nch; ++ci) {
            __syncthreads();
            const int cc = ci + 1;
            if (w < 4 && cc < nch) {
                const int s0 = (cc == 0) ? t0 : (cc - 1) * 64;
                const int par = cc & 1;
                f32x4 sf[4];
#pragma unroll
                for (int st = 0; st < 4; ++st) sf[st] = (f32x4){0.f, 0.f, 0.f, 0.f};
#pragma unroll
                for (int st = 0; st < 4; ++st)
#pragma unroll
                    for (int ks = 0; ks < 2; ++ks) {
                        bf16x8 kf = *(const bf16x8*)(xbb +
                            (size_t)(s0 + st * 16 + l16) * 1024 + h * 64 + ks * 32 + q * 8);
                        sf[st] = MFMA16(qf[ks], kf, sf[st]);
                    }
                float mx[4] = {-3.0e38f, -3.0e38f, -3.0e38f, -3.0e38f};
#pragma unroll
                for (int st = 0; st < 4; ++st)
#pragma unroll
                    for (int r = 0; r < 4; ++r) {
                        float v = sf[st][r] * 0.25f;
                        if (cc == 0 && (s0 + st * 16 + l16) > (t0 + g * 16 + q * 4 + r))
                            v = -3.0e38f;
                        sf[st][r] = v;
                        mx[r] = fmaxf(mx[r], v);
                    }
#pragma unroll
                for (int r = 0; r < 4; ++r) {
                    mx[r] = fmaxf(mx[r], __shfl_xor(mx[r], 1));
                    mx[r] = fmaxf(mx[r], __shfl_xor(mx[r], 2));
                    mx[r] = fmaxf(mx[r], __shfl_xor(mx[r], 4));
                    mx[r] = fmaxf(mx[r], __shfl_xor(mx[r], 8));
                }
                float sum[4], al[4];
                int upd = 0;
#pragma unroll
                for (int r = 0; r < 4; ++r) {
                    float m_new = fmaxf(m_r[r], mx[r]);
                    al[r] = __expf(m_r[r] - m_new);
                    upd |= (m_new > m_r[r]) ? 1 : 0;
                    m_r[r] = m_new;
                    sum[r] = 0.f;
                }
#pragma unroll
                for (int st = 0; st < 4; ++st)
#pragma unroll
                    for (int r = 0; r < 4; ++r) {
                        float pv = __expf(sf[st][r] - m_r[r]);
                        sum[r] += pv;
                        Pb[par][g * 16 + q * 4 + r][st * 16 + l16] = f2bf(pv);
                    }
#pragma unroll
                for (int r = 0; r < 4; ++r) {
                    sum[r] += __shfl_xor(sum[r], 1);
                    sum[r] += __shfl_xor(sum[r], 2);
                    sum[r] += __shfl_xor(sum[r], 4);
                    sum[r] += __shfl_xor(sum[r], 8);
                    l_r[r] = l_r[r] * al[r] + sum[r];
                }
                if (l16 == 0) {
#pragma unroll
                    for (int r = 0; r < 4; ++r) row_al[par][g * 16 + q * 4 + r] = al[r];
                }
                int any_upd = __any(upd);
                if (lane == 0) flags[par][g] = any_upd;
            }
            if (ci >= 0) {
                const int par = ci & 1;
                if (flags[par][0] | flags[par][1] | flags[par][2] | flags[par][3]) {
#pragma unroll
                    for (int mt = 0; mt < 4; ++mt) {
                        float a0 = row_al[par][mt * 16 + q * 4 + 0];
                        float a1 = row_al[par][mt * 16 + q * 4 + 1];
                        float a2 = row_al[par][mt * 16 + q * 4 + 2];
                        float a3 = row_al[par][mt * 16 + q * 4 + 3];
#pragma unroll
                        for (int nt = 0; nt < 8; ++nt) {
                            acc[mt][nt][0] *= a0;
                            acc[mt][nt][1] *= a1;
                            acc[mt][nt][2] *= a2;
                            acc[mt][nt][3] *= a3;
                        }
                    }
                }
                bf16x8 pf[4][2];
#pragma unroll
                for (int mt = 0; mt < 4; ++mt)
#pragma unroll
                    for (int ks = 0; ks < 2; ++ks)
                        pf[mt][ks] = *(bf16x8*)&Pb[par][mt * 16 + l16][ks * 32 + q * 8];
                const int s0p = (ci == 0) ? t0 : (ci - 1) * 64;
#pragma unroll
                for (int nt = 0; nt < 8; ++nt)
#pragma unroll
                    for (int ks = 0; ks < 2; ++ks) {
                        bf16x8 vf = *(const bf16x8*)(ztb +
                            (size_t)(nw + nt * 16 + l16) * 1024 + s0p + ks * 32 + q * 8);
#pragma unroll
                        for (int mt = 0; mt < 4; ++mt)
                            acc[mt][nt] = MFMA16(pf[mt][ks], vf, acc[mt][nt]);
                    }
            }
        }

        if (w < 4 && l16 == 0) {
#pragma unroll
            for (int r = 0; r < 4; ++r) row_l[g * 16 + q * 4 + r] = l_r[r];
        }
        __syncthreads();
#pragma unroll
        for (int mt = 0; mt < 4; ++mt) {
            float i0 = 1.f / row_l[mt * 16 + q * 4 + 0];
            float i1 = 1.f / row_l[mt * 16 + q * 4 + 1];
            float i2 = 1.f / row_l[mt * 16 + q * 4 + 2];
            float i3 = 1.f / row_l[mt * 16 + q * 4 + 3];
#pragma unroll
            for (int nt = 0; nt < 8; ++nt) {
                size_t base = (size_t)(b * 1024 + t0 + mt * 16 + q * 4) * 1024 +
                              nw + nt * 16 + l16;
                atomicAdd(out + base,            acc[mt][nt][0] * i0);
                atomicAdd(out + base + 1024,     acc[mt][nt][1] * i1);
                atomicAdd(out + base + 2048,     acc[mt][nt][2] * i2);
                atomicAdd(out + base + 3072,     acc[mt][nt][3] * i3);
            }
        }
        __syncthreads();
    }
}

// ---------------------------------------------------------------------------
extern "C" void kernel_launch(void* const* d_in, const int* in_sizes, int n_in,
                              void* d_out, int out_size, void* d_ws, size_t ws_size,
                              hipStream_t stream) {
    const float* x = (const float*)d_in[0];
    // d_in[1] (mask) recomputed analytically.
    const float* W = (const float*)d_in[2];
    float* out = (float*)d_out;

    hipMemsetAsync(d_out, 0, (size_t)B_ * T_ * C_ * sizeof(float), stream);

    if (ws_size >= (size_t)104 * 1024 * 1024) {
        // O = P@x per head (plain stores), then one long-K GEMM.
        // ws layout (shorts): xb[0,2M) xbT[2M,4M) Wt[4M,20M) O[20M,52M)
        short* xb  = (short*)d_ws;
        short* xbT = xb + (size_t)2 * 1024 * 1024;
        short* Wt  = xb + (size_t)4 * 1024 * 1024;
        short* O   = xb + (size_t)20 * 1024 * 1024;

        cvt_x<<<(B_ * T_ * C_) / (256 * 8), 256, 0, stream>>>(x, xb);
        cvt_w<<<B_ * 16 * 16, 256, 0, stream>>>(x, xbT);   // xbT[b][c][s]
        cvt_w<<<16 * 16 * 16, 256, 0, stream>>>(W, Wt);    // Wt[h][n][c]
        attn_po<<<512, 512, 0, stream>>>(xb, xbT, O);
        ogemm<<<512, 256, 0, stream>>>(O, Wt, out);
    } else {
        // Fallback: round-0 proven pipeline.
        short* xb = (short*)d_ws;                              // 4 MiB
        short* ZT = (short*)d_ws + (size_t)B_ * T_ * C_;       // 64 MiB
        short* Wt = ZT + (size_t)B_ * H_ * 1024 * 1024;        // 32 MiB

        const bool big_ws = ws_size >= (size_t)100 * 1024 * 1024;
        cvt_x<<<(B_ * T_ * C_) / (256 * 8), 256, 0, stream>>>(x, xb);
        if (big_ws) {
            cvt_w<<<16 * 16 * 16, 256, 0, stream>>>(W, Wt);
            zgemm_fast<<<16 * 16 * 8, 256, 0, stream>>>(xb, Wt, ZT);
        } else {
            zgemm_sm<<<H_ * 8 * 8, 256, 0, stream>>>(xb, W, ZT);
        }
        attn<<<256, 512, 0, stream>>>(xb, ZT, out);
    }
}

// Round 12
// 369.458 us; speedup vs baseline: 1.0407x; 1.0407x over previous
//
#include <hip/hip_runtime.h>
#include <hip/hip_bf16.h>

#define B_ 2
#define T_ 1024
#define C_ 1024
#define H_ 16

typedef short bf16x8 __attribute__((ext_vector_type(8)));
typedef float f32x4 __attribute__((ext_vector_type(4)));

#define MFMA16(a, b, c) __builtin_amdgcn_mfma_f32_16x16x32_bf16(a, b, c, 0, 0, 0)

__device__ inline short f2bf(float x) {
    union { __hip_bfloat16 h; short s; } u;
    u.h = __float2bfloat16(x);
    return u.s;
}

__device__ inline void gl_lds16(const void* g, void* l) {
    __builtin_amdgcn_global_load_lds(
        (const __attribute__((address_space(1))) unsigned int*)g,
        (__attribute__((address_space(3))) unsigned int*)l, 16, 0, 0);
}

// ---------------------------------------------------------------------------
// Kernel: x (fp32) -> xb (bf16), flat. 2M elems, 8/thread. (fallback path)
// ---------------------------------------------------------------------------
__global__ __launch_bounds__(256) void cvt_x(const float* __restrict__ x,
                                             short* __restrict__ xb) {
    int idx = (blockIdx.x * 256 + threadIdx.x) * 8;
    float4 a = *(const float4*)(x + idx);
    float4 b = *(const float4*)(x + idx + 4);
    bf16x8 v;
    v[0] = f2bf(a.x); v[1] = f2bf(a.y); v[2] = f2bf(a.z); v[3] = f2bf(a.w);
    v[4] = f2bf(b.x); v[5] = f2bf(b.y); v[6] = f2bf(b.z); v[7] = f2bf(b.w);
    *(bf16x8*)(xb + idx) = v;
}

// ---------------------------------------------------------------------------
// Kernel: generic fp32->bf16 64x64 tile transpose (fallback path).
// ---------------------------------------------------------------------------
__global__ __launch_bounds__(256) void cvt_w(const float* __restrict__ W,
                                             short* __restrict__ Wt) {
    __shared__ float T[64][65];
    const int bid = blockIdx.x;
    const int nb = bid & 15, cb = (bid >> 4) & 15, h = bid >> 8;
    const int t = threadIdx.x;
    const int c0 = cb * 64, n0 = nb * 64;
    const float* src = W + (size_t)(h * 1024 + c0) * 1024 + n0;
    {
        const int cl = t >> 4, nl = (t & 15) * 4;
#pragma unroll
        for (int r = 0; r < 4; ++r) {
            float4 v = *(const float4*)(src + (size_t)(cl + r * 16) * 1024 + nl);
            T[cl + r * 16][nl + 0] = v.x;
            T[cl + r * 16][nl + 1] = v.y;
            T[cl + r * 16][nl + 2] = v.z;
            T[cl + r * 16][nl + 3] = v.w;
        }
    }
    __syncthreads();
    {
        short* dst = Wt + (size_t)(h * 1024 + n0) * 1024 + c0;
        const int nl = t >> 3, cl8 = (t & 7) * 8;
#pragma unroll
        for (int r = 0; r < 2; ++r) {
            const int n = nl + r * 32;
            bf16x8 o;
#pragma unroll
            for (int j = 0; j < 8; ++j) o[j] = f2bf(T[cl8 + j][n]);
            *(bf16x8*)(dst + (size_t)n * 1024 + cl8) = o;
        }
    }
}

// ---------------------------------------------------------------------------
// Kernel: cvt_fused — one launch replaces cvt_x + cvt_w(xbT) + cvt_w(Wt).
// Blocks 0..511:   xbT[b][ch][s] = bf16(x[b][s][ch])  AND  xb straight-thru
//                  (both emitted from the same LDS tile -> x read ONCE).
// Blocks 512..4607: Wt[h][n][c] = bf16(W[h*1024+c][n])  (bid-512).
// ---------------------------------------------------------------------------
__global__ __launch_bounds__(256) void cvt_fused(const float* __restrict__ x,
                                                 const float* __restrict__ W,
                                                 short* __restrict__ xb,
                                                 short* __restrict__ xbT,
                                                 short* __restrict__ Wt) {
    __shared__ float T[64][65];
    const int bid0 = blockIdx.x;
    const bool isX = bid0 < 512;
    const int bid = isX ? bid0 : bid0 - 512;
    const float* srcb = isX ? x : W;
    short* dstb = isX ? xbT : Wt;
    const int nb = bid & 15, cb = (bid >> 4) & 15, g = bid >> 8;
    const int t = threadIdx.x;
    const int c0 = cb * 64, n0 = nb * 64;
    const float* src = srcb + (size_t)(g * 1024 + c0) * 1024 + n0;
    {
        const int cl = t >> 4, nl = (t & 15) * 4;
#pragma unroll
        for (int r = 0; r < 4; ++r) {
            float4 v = *(const float4*)(src + (size_t)(cl + r * 16) * 1024 + nl);
            T[cl + r * 16][nl + 0] = v.x;
            T[cl + r * 16][nl + 1] = v.y;
            T[cl + r * 16][nl + 2] = v.z;
            T[cl + r * 16][nl + 3] = v.w;
        }
    }
    __syncthreads();
    {
        short* dst = dstb + (size_t)(g * 1024 + n0) * 1024 + c0;
        const int nl = t >> 3, cl8 = (t & 7) * 8;
#pragma unroll
        for (int r = 0; r < 2; ++r) {
            const int n = nl + r * 32;
            bf16x8 o;
#pragma unroll
            for (int j = 0; j < 8; ++j) o[j] = f2bf(T[cl8 + j][n]);
            *(bf16x8*)(dst + (size_t)n * 1024 + cl8) = o;
        }
    }
    if (isX) {
        // straight-through xb[b][token][ch]: row = token (src row), col = ch.
        const int rl = t >> 3, c8 = (t & 7) * 8;
#pragma unroll
        for (int rr = 0; rr < 2; ++rr) {
            const int row = rl + rr * 32;
            bf16x8 o;
#pragma unroll
            for (int j = 0; j < 8; ++j) o[j] = f2bf(T[row][c8 + j]);
            *(bf16x8*)(xb + (size_t)(g * 1024 + c0 + row) * 1024 + n0 + c8) = o;
        }
    }
}

// ---------------------------------------------------------------------------
// Kernel: attn_po v3 (round-6/8/9/10 proven, ~155 us). UNCHANGED.
// ---------------------------------------------------------------------------
__global__ __launch_bounds__(512, 2) void attn_po(const short* __restrict__ xb,
                                                  const short* __restrict__ xbT,
                                                  short* __restrict__ O) {
    __shared__ short Pb[2][64][72];     // probs bf16, double-buffered
    __shared__ float row_al[2][64];
    __shared__ float row_l[64];
    __shared__ int   flags[2][4];

    const int tid = threadIdx.x;
    const int bh = blockIdx.x & 31;                  // XCD-pinned (b,h)
    const int rest = blockIdx.x >> 5;                // 0..15
    const int tb = (rest < 8) ? rest : 23 - rest;    // pair long+short tiles
    const int b = bh >> 4, h = bh & 15;
    const int lane = tid & 63, q = lane >> 4, l16 = lane & 15;
    const int w = tid >> 6;
    const int g = w & 3;          // QK row-group
    const int nw = w * 128;       // PV channel base
    const short* xbb = xb + ((size_t)b << 20);
    const short* vtb = xbT + ((size_t)b << 20);   // [c][s], s contiguous

    const int t0 = tb * 64;
    const int nch = tb + 1;

    f32x4 acc[4][8];
#pragma unroll
    for (int mt = 0; mt < 4; ++mt)
#pragma unroll
        for (int nt = 0; nt < 8; ++nt) acc[mt][nt] = (f32x4){0.f, 0.f, 0.f, 0.f};
    float m_r[4], l_r[4];
#pragma unroll
    for (int r = 0; r < 4; ++r) { m_r[r] = -3.0e38f; l_r[r] = 0.f; }

    bf16x8 qf[2];
    if (w < 4) {
#pragma unroll
        for (int ks = 0; ks < 2; ++ks)
            qf[ks] = *(const bf16x8*)(xbb + (size_t)(t0 + g * 16 + l16) * 1024 +
                                      h * 64 + ks * 32 + q * 8);
    }

    for (int ci = -1; ci < nch; ++ci) {
        __syncthreads();
        const int cc = ci + 1;
        if (w < 4 && cc < nch) {
            const int s0 = (cc == 0) ? t0 : (cc - 1) * 64;
            const int par = cc & 1;
            // QK^T
            f32x4 sf[4];
#pragma unroll
            for (int st = 0; st < 4; ++st) sf[st] = (f32x4){0.f, 0.f, 0.f, 0.f};
#pragma unroll
            for (int st = 0; st < 4; ++st)
#pragma unroll
                for (int ks = 0; ks < 2; ++ks) {
                    bf16x8 kf = *(const bf16x8*)(xbb +
                        (size_t)(s0 + st * 16 + l16) * 1024 + h * 64 + ks * 32 + q * 8);
                    sf[st] = MFMA16(qf[ks], kf, sf[st]);
                }
            // In-register online softmax (rows q*4+r of group g)
            float mx[4] = {-3.0e38f, -3.0e38f, -3.0e38f, -3.0e38f};
#pragma unroll
            for (int st = 0; st < 4; ++st)
#pragma unroll
                for (int r = 0; r < 4; ++r) {
                    float v = sf[st][r] * 0.25f;
                    if (cc == 0 && (s0 + st * 16 + l16) > (t0 + g * 16 + q * 4 + r))
                        v = -3.0e38f;
                    sf[st][r] = v;
                    mx[r] = fmaxf(mx[r], v);
                }
#pragma unroll
            for (int r = 0; r < 4; ++r) {
                mx[r] = fmaxf(mx[r], __shfl_xor(mx[r], 1));
                mx[r] = fmaxf(mx[r], __shfl_xor(mx[r], 2));
                mx[r] = fmaxf(mx[r], __shfl_xor(mx[r], 4));
                mx[r] = fmaxf(mx[r], __shfl_xor(mx[r], 8));
            }
            float sum[4], al[4];
            int upd = 0;
#pragma unroll
            for (int r = 0; r < 4; ++r) {
                float m_new = fmaxf(m_r[r], mx[r]);
                al[r] = __expf(m_r[r] - m_new);
                upd |= (m_new > m_r[r]) ? 1 : 0;
                m_r[r] = m_new;
                sum[r] = 0.f;
            }
#pragma unroll
            for (int st = 0; st < 4; ++st)
#pragma unroll
                for (int r = 0; r < 4; ++r) {
                    float pv = __expf(sf[st][r] - m_r[r]);
                    sum[r] += pv;
                    Pb[par][g * 16 + q * 4 + r][st * 16 + l16] = f2bf(pv);
                }
#pragma unroll
            for (int r = 0; r < 4; ++r) {
                sum[r] += __shfl_xor(sum[r], 1);
                sum[r] += __shfl_xor(sum[r], 2);
                sum[r] += __shfl_xor(sum[r], 4);
                sum[r] += __shfl_xor(sum[r], 8);
                l_r[r] = l_r[r] * al[r] + sum[r];
            }
            if (l16 == 0) {
#pragma unroll
                for (int r = 0; r < 4; ++r) row_al[par][g * 16 + q * 4 + r] = al[r];
            }
            int any_upd = __any(upd);
            if (lane == 0) flags[par][g] = any_upd;
        }
        if (ci >= 0) {
            const int par = ci & 1;
            // Rescale accumulators only if some row max moved.
            if (flags[par][0] | flags[par][1] | flags[par][2] | flags[par][3]) {
#pragma unroll
                for (int mt = 0; mt < 4; ++mt) {
                    float a0 = row_al[par][mt * 16 + q * 4 + 0];
                    float a1 = row_al[par][mt * 16 + q * 4 + 1];
                    float a2 = row_al[par][mt * 16 + q * 4 + 2];
                    float a3 = row_al[par][mt * 16 + q * 4 + 3];
#pragma unroll
                    for (int nt = 0; nt < 8; ++nt) {
                        acc[mt][nt][0] *= a0;
                        acc[mt][nt][1] *= a1;
                        acc[mt][nt][2] *= a2;
                        acc[mt][nt][3] *= a3;
                    }
                }
            }
            // PV: V-fragments from xbT (L2-hot), point-of-use.
            bf16x8 pf[4][2];
#pragma unroll
            for (int mt = 0; mt < 4; ++mt)
#pragma unroll
                for (int ks = 0; ks < 2; ++ks)
                    pf[mt][ks] = *(bf16x8*)&Pb[par][mt * 16 + l16][ks * 32 + q * 8];
            const int s0p = (ci == 0) ? t0 : (ci - 1) * 64;
#pragma unroll
            for (int nt = 0; nt < 8; ++nt)
#pragma unroll
                for (int ks = 0; ks < 2; ++ks) {
                    bf16x8 vf = *(const bf16x8*)(vtb +
                        (size_t)(nw + nt * 16 + l16) * 1024 + s0p + ks * 32 + q * 8);
#pragma unroll
                    for (int mt = 0; mt < 4; ++mt)
                        acc[mt][nt] = MFMA16(pf[mt][ks], vf, acc[mt][nt]);
                }
        }
    }

    // Epilogue: share row sums, normalize, PLAIN bf16 stores to O.
    if (w < 4 && l16 == 0) {
#pragma unroll
        for (int r = 0; r < 4; ++r) row_l[g * 16 + q * 4 + r] = l_r[r];
    }
    __syncthreads();
    short* ob = O + ((((size_t)(b * 1024 + t0) * 16) + h) << 10);
#pragma unroll
    for (int mt = 0; mt < 4; ++mt) {
        float i0 = 1.f / row_l[mt * 16 + q * 4 + 0];
        float i1 = 1.f / row_l[mt * 16 + q * 4 + 1];
        float i2 = 1.f / row_l[mt * 16 + q * 4 + 2];
        float i3 = 1.f / row_l[mt * 16 + q * 4 + 3];
#pragma unroll
        for (int nt = 0; nt < 8; ++nt) {
            size_t base = (size_t)(mt * 16 + q * 4) * 16384 + nw + nt * 16 + l16;
            ob[base]         = f2bf(acc[mt][nt][0] * i0);
            ob[base + 16384] = f2bf(acc[mt][nt][1] * i1);
            ob[base + 32768] = f2bf(acc[mt][nt][2] * i2);
            ob[base + 49152] = f2bf(acc[mt][nt][3] * i3);
        }
    }
}

// ---------------------------------------------------------------------------
// Kernel: ogemm v8 — out[m][n] += O[m][k] * Wt[k->(h,c)][n], 128m x 256n tile.
// Round-11's dbuf regressed (3rd pipelining failure -> abandoned). Model from
// R8-R10: per-CU time ~= blocks/CU * steps/block * step-serial-time / ~2,
// and every prior knob preserved blocks*steps. This version HALVES per-CU
// step-serials via a fatter tile: 128x256 output (acc[4][8]=128 VGPR, cap
// 256 at (256,2)), BK=64, split-K 8 with the R9-PROVEN kq-per-XCD swizzle
// (FETCH held 63 MB there). Grid 512 = 16m x 4n x 8kq, 2 blocks/CU, 32
// steps/block (vs v6's 64): per step 12 staging loads (A 16KB + B 32KB,
// single-buffer 48KB LDS) and 512 MFMA. Watch: VGPR ~200 no scratch,
// MfmaUtil -> 25-35, FETCH 65-85 MB.
// Epilogue: fp32 atomicAdd (out pre-zeroed), 16.8M atomics (R9 level, fine).
// ---------------------------------------------------------------------------
__global__ __launch_bounds__(256, 2) void ogemm(const short* __restrict__ O,
                                                const short* __restrict__ Wt,
                                                float* __restrict__ out) {
    __shared__ short Al[8][128][8];   // [kgrp][m][8k]  16 KiB
    __shared__ short Bl[8][256][8];   // [kgrp][n][8k]  32 KiB

    const int orig = blockIdx.x;                   // HW: XCD = orig & 7
    const int x = orig & 7, j = orig >> 3;         // j in 0..63
    const int kq  = x;                             // one kq per XCD (R9 map)
    const int m_t = j >> 2;                        // 0..15 (slow)
    const int n_t = j & 3;                         // 0..3  (fast: O reuse)
    const int m0 = m_t * 128, n0 = n_t * 256;
    const int t = threadIdx.x;
    const int lane = t & 63, q = lane >> 4, l16 = lane & 15;
    const int wv = t >> 6;
    const int wm = (wv & 1) * 64, wn = (wv >> 1) * 128;

    const short* Ab = O + (size_t)m0 * 16384;
    const int srow = t & 127, skg = t >> 7;        // A staging row / k-group

    char* al_base = (char*)&Al[0][0][0] + (size_t)t * 16;  // (skg, srow)
    char* bl_base = (char*)&Bl[0][0][0] + (size_t)t * 16;  // (kg0, row t)

    f32x4 acc[4][8];
#pragma unroll
    for (int i = 0; i < 4; ++i)
#pragma unroll
        for (int j2 = 0; j2 < 8; ++j2) acc[i][j2] = (f32x4){0.f, 0.f, 0.f, 0.f};

    const int kbase = kq * 2048;                   // 2048 K per split (8 way)
    for (int kk = 0; kk < 2048; kk += 64) {
        const int k0 = kbase + kk;
        const int h = k0 >> 10, c0 = k0 & 1023;    // BK=64 never straddles h
        const short* Arow = Ab + (size_t)srow * 16384 + k0;
        const short* Brow = Wt + ((size_t)h << 20) + (size_t)(n0 + t) * 1024 + c0;
        __syncthreads();
        // A: 128 rows x 8 kgrps, 4 loads/thread (kg = skg, skg+2, skg+4, skg+6)
#pragma unroll
        for (int jj = 0; jj < 4; ++jj)
            gl_lds16(Arow + (2 * jj + skg) * 8, al_base + jj * 4096);
        // B: 256 rows (row = t) x 8 kgrps, 8 loads/thread
#pragma unroll
        for (int kg = 0; kg < 8; ++kg)
            gl_lds16(Brow + kg * 8, bl_base + kg * 4096);
        __syncthreads();
#pragma unroll
        for (int ks = 0; ks < 2; ++ks) {
            bf16x8 af[4], bfr[8];
#pragma unroll
            for (int i = 0; i < 4; ++i)
                af[i] = *(bf16x8*)&Al[q + 4 * ks][wm + i * 16 + l16][0];
#pragma unroll
            for (int j2 = 0; j2 < 8; ++j2)
                bfr[j2] = *(bf16x8*)&Bl[q + 4 * ks][wn + j2 * 16 + l16][0];
#pragma unroll
            for (int i = 0; i < 4; ++i)
#pragma unroll
                for (int j2 = 0; j2 < 8; ++j2)
                    acc[i][j2] = MFMA16(af[i], bfr[j2], acc[i][j2]);
        }
    }

    // Epilogue: out[m][n] atomic add (split-K partial).
#pragma unroll
    for (int i = 0; i < 4; ++i)
#pragma unroll
        for (int j2 = 0; j2 < 8; ++j2)
#pragma unroll
            for (int r = 0; r < 4; ++r) {
                int m = m0 + wm + i * 16 + q * 4 + r;
                int n = n0 + wn + j2 * 16 + l16;
                atomicAdd(out + (size_t)m * 1024 + n, acc[i][j2][r]);
            }
}

// ---------------------------------------------------------------------------
// Fallback path kernels (round-0 proven): zgemm_fast/zgemm_sm + atomic attn.
// ---------------------------------------------------------------------------
__global__ __launch_bounds__(256, 4) void zgemm_fast(const short* __restrict__ xb,
                                                     const short* __restrict__ Wt,
                                                     short* __restrict__ ZT) {
    __shared__ short Al[4][128][8];
    __shared__ short Bl[4][128][8];

    const int bid = blockIdx.x;
    const int n_t = bid & 7, h = (bid >> 3) & 15, s_t = bid >> 7;
    const int n0 = n_t * 128, s0g = s_t * 128;
    const int t = threadIdx.x;
    const int lane = t & 63, q = lane >> 4, l16 = lane & 15;
    const int wv = t >> 6;
    const int wm = (wv & 1) * 64, wn = (wv >> 1) * 64;

    const short* Ab = Wt + ((size_t)h * 1024 + n0) * 1024;
    const short* Bb = xb + (size_t)s0g * 1024;
    const int srow = t & 127, skg = t >> 7;

    char* al_base = (char*)&Al[0][0][0] + (size_t)t * 16;
    char* bl_base = (char*)&Bl[0][0][0] + (size_t)t * 16;

    f32x4 acc[4][4];
#pragma unroll
    for (int i = 0; i < 4; ++i)
#pragma unroll
        for (int j = 0; j < 4; ++j) acc[i][j] = (f32x4){0.f, 0.f, 0.f, 0.f};

    for (int k0 = 0; k0 < 1024; k0 += 32) {
        __syncthreads();
        gl_lds16(Ab + (size_t)srow * 1024 + k0 + skg * 8, al_base);
        gl_lds16(Ab + (size_t)srow * 1024 + k0 + (skg + 2) * 8, al_base + 4096);
        gl_lds16(Bb + (size_t)srow * 1024 + k0 + skg * 8, bl_base);
        gl_lds16(Bb + (size_t)srow * 1024 + k0 + (skg + 2) * 8, bl_base + 4096);
        __syncthreads();
        bf16x8 af[4], bfr[4];
#pragma unroll
        for (int i = 0; i < 4; ++i) af[i] = *(bf16x8*)&Al[q][wm + i * 16 + l16][0];
#pragma unroll
        for (int j = 0; j < 4; ++j) bfr[j] = *(bf16x8*)&Bl[q][wn + j * 16 + l16][0];
#pragma unroll
        for (int i = 0; i < 4; ++i)
#pragma unroll
            for (int j = 0; j < 4; ++j)
                acc[i][j] = MFMA16(af[i], bfr[j], acc[i][j]);
    }

    const int b = s0g >> 10, s_in0 = s0g & 1023;
    short* zb = ZT + ((size_t)(b * 16 + h) << 20);
#pragma unroll
    for (int i = 0; i < 4; ++i)
#pragma unroll
        for (int j = 0; j < 4; ++j)
#pragma unroll
            for (int r = 0; r < 4; ++r) {
                int n = n0 + wm + i * 16 + q * 4 + r;
                int s = s_in0 + wn + j * 16 + l16;
                zb[(size_t)n * 1024 + s] = f2bf(acc[i][j][r]);
            }
}

#define ZPAD 40

__global__ __launch_bounds__(256, 2) void zgemm_sm(const short* __restrict__ xb,
                                                   const float* __restrict__ W,
                                                   short* __restrict__ ZT) {
    __shared__ short Wts[128 * ZPAD];
    __shared__ short Xs[2][128 * ZPAD];

    const int tid = threadIdx.x;
    const int bs = blockIdx.x & 7;
    const int bn = (blockIdx.x >> 3) & 7;
    const int h  = blockIdx.x >> 6;
    const int s0 = bs * 128, n0 = bn * 128;
    const int lane = tid & 63, q = lane >> 4, l16 = lane & 15;
    const int w = tid >> 6, bw = w >> 1, sh = w & 1;

    f32x4 acc[8][4];
#pragma unroll
    for (int i = 0; i < 8; ++i)
#pragma unroll
        for (int j = 0; j < 4; ++j) acc[i][j] = (f32x4){0.f, 0.f, 0.f, 0.f};

    for (int k0 = 0; k0 < 1024; k0 += 32) {
        __syncthreads();
#pragma unroll
        for (int r = 0; r < 2; ++r) {
            const int c2 = ((tid >> 5) << 1) + (r << 4);
            const float* w0p = W + (size_t)(h * 1024 + k0 + c2) * 1024 + n0;
            const float* w1p = w0p + 1024;
#pragma unroll
            for (int i = 0; i < 4; ++i) {
                const int n = (tid & 31) + (i << 5);
                float wa = w0p[n], wb = w1p[n];
                unsigned u = (unsigned)(unsigned short)f2bf(wa) |
                             ((unsigned)(unsigned short)f2bf(wb) << 16);
                *(unsigned*)&Wts[n * ZPAD + c2] = u;
            }
        }
#pragma unroll
        for (int i = 0; i < 4; ++i) {
            const int id = tid + (i << 8);
            const int b2 = id >> 9, s = (id >> 2) & 127, cg = id & 3;
            bf16x8 v = *(const bf16x8*)(xb + (size_t)b2 * (T_ * C_) +
                                        (size_t)(s0 + s) * 1024 + k0 + cg * 8);
            *(bf16x8*)&Xs[b2][s * ZPAD + cg * 8] = v;
        }
        __syncthreads();

        bf16x8 af[8], bfr[4];
#pragma unroll
        for (int nt = 0; nt < 8; ++nt)
            af[nt] = *(bf16x8*)&Wts[(nt * 16 + l16) * ZPAD + q * 8];
#pragma unroll
        for (int st = 0; st < 4; ++st)
            bfr[st] = *(bf16x8*)&Xs[bw][(sh * 64 + st * 16 + l16) * ZPAD + q * 8];
#pragma unroll
        for (int nt = 0; nt < 8; ++nt)
#pragma unroll
            for (int st = 0; st < 4; ++st)
                acc[nt][st] = MFMA16(af[nt], bfr[st], acc[nt][st]);
    }

    short* zb = ZT + (size_t)(bw * 16 + h) * (1024 * 1024);
#pragma unroll
    for (int nt = 0; nt < 8; ++nt)
#pragma unroll
        for (int st = 0; st < 4; ++st)
#pragma unroll
            for (int r = 0; r < 4; ++r) {
                int n_abs = n0 + nt * 16 + q * 4 + r;
                int s_abs = s0 + sh * 64 + st * 16 + l16;
                zb[(size_t)n_abs * 1024 + s_abs] = f2bf(acc[nt][st][r]);
            }
}

__global__ __launch_bounds__(512, 2) void attn(const short* __restrict__ xb,
                                               const short* __restrict__ ZT,
                                               float* __restrict__ out) {
    __shared__ short Pb[2][64][72];
    __shared__ float row_al[2][64];
    __shared__ float row_l[64];
    __shared__ int   flags[2][4];

    const int tid = threadIdx.x;
    const int bh = blockIdx.x & 31, p = blockIdx.x >> 5;
    const int b = bh >> 4, h = bh & 15;
    const int lane = tid & 63, q = lane >> 4, l16 = lane & 15;
    const int w = tid >> 6;
    const int g = w & 3;
    const int nw = w * 128;
    const short* xbb = xb + ((size_t)b << 20);
    const short* ztb = ZT + ((size_t)(b * 16 + h) << 20);

    const int tiles[2] = { p, 15 - p };
    for (int ti = 0; ti < 2; ++ti) {
        const int tb = tiles[ti];
        const int t0 = tb * 64;
        const int nch = tb + 1;

        f32x4 acc[4][8];
#pragma unroll
        for (int mt = 0; mt < 4; ++mt)
#pragma unroll
            for (int nt = 0; nt < 8; ++nt) acc[mt][nt] = (f32x4){0.f, 0.f, 0.f, 0.f};
        float m_r[4], l_r[4];
#pragma unroll
        for (int r = 0; r < 4; ++r) { m_r[r] = -3.0e38f; l_r[r] = 0.f; }

        bf16x8 qf[2];
        if (w < 4) {
#pragma unroll
            for (int ks = 0; ks < 2; ++ks)
                qf[ks] = *(const bf16x8*)(xbb + (size_t)(t0 + g * 16 + l16) * 1024 +
                                          h * 64 + ks * 32 + q * 8);
        }

        for (int ci = -1; ci < nch; ++ci) {
            __syncthreads();
            const int cc = ci + 1;
            if (w < 4 && cc < nch) {
                const int s0 = (cc == 0) ? t0 : (cc - 1) * 64;
                const int par = cc & 1;
                f32x4 sf[4];
#pragma unroll
                for (int st = 0; st < 4; ++st) sf[st] = (f32x4){0.f, 0.f, 0.f, 0.f};
#pragma unroll
                for (int st = 0; st < 4; ++st)
#pragma unroll
                    for (int ks = 0; ks < 2; ++ks) {
                        bf16x8 kf = *(const bf16x8*)(xbb +
                            (size_t)(s0 + st * 16 + l16) * 1024 + h * 64 + ks * 32 + q * 8);
                        sf[st] = MFMA16(qf[ks], kf, sf[st]);
                    }
                float mx[4] = {-3.0e38f, -3.0e38f, -3.0e38f, -3.0e38f};
#pragma unroll
                for (int st = 0; st < 4; ++st)
#pragma unroll
                    for (int r = 0; r < 4; ++r) {
                        float v = sf[st][r] * 0.25f;
                        if (cc == 0 && (s0 + st * 16 + l16) > (t0 + g * 16 + q * 4 + r))
                            v = -3.0e38f;
                        sf[st][r] = v;
                        mx[r] = fmaxf(mx[r], v);
                    }
#pragma unroll
                for (int r = 0; r < 4; ++r) {
                    mx[r] = fmaxf(mx[r], __shfl_xor(mx[r], 1));
                    mx[r] = fmaxf(mx[r], __shfl_xor(mx[r], 2));
                    mx[r] = fmaxf(mx[r], __shfl_xor(mx[r], 4));
                    mx[r] = fmaxf(mx[r], __shfl_xor(mx[r], 8));
                }
                float sum[4], al[4];
                int upd = 0;
#pragma unroll
                for (int r = 0; r < 4; ++r) {
                    float m_new = fmaxf(m_r[r], mx[r]);
                    al[r] = __expf(m_r[r] - m_new);
                    upd |= (m_new > m_r[r]) ? 1 : 0;
                    m_r[r] = m_new;
                    sum[r] = 0.f;
                }
#pragma unroll
                for (int st = 0; st < 4; ++st)
#pragma unroll
                    for (int r = 0; r < 4; ++r) {
                        float pv = __expf(sf[st][r] - m_r[r]);
                        sum[r] += pv;
                        Pb[par][g * 16 + q * 4 + r][st * 16 + l16] = f2bf(pv);
                    }
#pragma unroll
                for (int r = 0; r < 4; ++r) {
                    sum[r] += __shfl_xor(sum[r], 1);
                    sum[r] += __shfl_xor(sum[r], 2);
                    sum[r] += __shfl_xor(sum[r], 4);
                    sum[r] += __shfl_xor(sum[r], 8);
                    l_r[r] = l_r[r] * al[r] + sum[r];
                }
                if (l16 == 0) {
#pragma unroll
                    for (int r = 0; r < 4; ++r) row_al[par][g * 16 + q * 4 + r] = al[r];
                }
                int any_upd = __any(upd);
                if (lane == 0) flags[par][g] = any_upd;
            }
            if (ci >= 0) {
                const int par = ci & 1;
                if (flags[par][0] | flags[par][1] | flags[par][2] | flags[par][3]) {
#pragma unroll
                    for (int mt = 0; mt < 4; ++mt) {
                        float a0 = row_al[par][mt * 16 + q * 4 + 0];
                        float a1 = row_al[par][mt * 16 + q * 4 + 1];
                        float a2 = row_al[par][mt * 16 + q * 4 + 2];
                        float a3 = row_al[par][mt * 16 + q * 4 + 3];
#pragma unroll
                        for (int nt = 0; nt < 8; ++nt) {
                            acc[mt][nt][0] *= a0;
                            acc[mt][nt][1] *= a1;
                            acc[mt][nt][2] *= a2;
                            acc[mt][nt][3] *= a3;
                        }
                    }
                }
                bf16x8 pf[4][2];
#pragma unroll
                for (int mt = 0; mt < 4; ++mt)
#pragma unroll
                    for (int ks = 0; ks < 2; ++ks)
                        pf[mt][ks] = *(bf16x8*)&Pb[par][mt * 16 + l16][ks * 32 + q * 8];
                const int s0p = (ci == 0) ? t0 : (ci - 1) * 64;
#pragma unroll
                for (int nt = 0; nt < 8; ++nt)
#pragma unroll
                    for (int ks = 0; ks < 2; ++ks) {
                        bf16x8 vf = *(const bf16x8*)(ztb +
                            (size_t)(nw + nt * 16 + l16) * 1024 + s0p + ks * 32 + q * 8);
#pragma unroll
                        for (int mt = 0; mt < 4; ++mt)
                            acc[mt][nt] = MFMA16(pf[mt][ks], vf, acc[mt][nt]);
                    }
            }
        }

        if (w < 4 && l16 == 0) {
#pragma unroll
            for (int r = 0; r < 4; ++r) row_l[g * 16 + q * 4 + r] = l_r[r];
        }
        __syncthreads();
#pragma unroll
        for (int mt = 0; mt < 4; ++mt) {
            float i0 = 1.f / row_l[mt * 16 + q * 4 + 0];
            float i1 = 1.f / row_l[mt * 16 + q * 4 + 1];
            float i2 = 1.f / row_l[mt * 16 + q * 4 + 2];
            float i3 = 1.f / row_l[mt * 16 + q * 4 + 3];
#pragma unroll
            for (int nt = 0; nt < 8; ++nt) {
                size_t base = (size_t)(b * 1024 + t0 + mt * 16 + q * 4) * 1024 +
                              nw + nt * 16 + l16;
                atomicAdd(out + base,            acc[mt][nt][0] * i0);
                atomicAdd(out + base + 1024,     acc[mt][nt][1] * i1);
                atomicAdd(out + base + 2048,     acc[mt][nt][2] * i2);
                atomicAdd(out + base + 3072,     acc[mt][nt][3] * i3);
            }
        }
        __syncthreads();
    }
}

// ---------------------------------------------------------------------------
extern "C" void kernel_launch(void* const* d_in, const int* in_sizes, int n_in,
                              void* d_out, int out_size, void* d_ws, size_t ws_size,
                              hipStream_t stream) {
    const float* x = (const float*)d_in[0];
    // d_in[1] (mask) recomputed analytically.
    const float* W = (const float*)d_in[2];
    float* out = (float*)d_out;

    hipMemsetAsync(d_out, 0, (size_t)B_ * T_ * C_ * sizeof(float), stream);

    if (ws_size >= (size_t)104 * 1024 * 1024) {
        // O = P@x per head (plain stores), then one long-K GEMM.
        // ws layout (shorts): xb[0,2M) xbT[2M,4M) Wt[4M,20M) O[20M,52M)
        short* xb  = (short*)d_ws;
        short* xbT = xb + (size_t)2 * 1024 * 1024;
        short* Wt  = xb + (size_t)4 * 1024 * 1024;
        short* O   = xb + (size_t)20 * 1024 * 1024;

        cvt_fused<<<512 + 4096, 256, 0, stream>>>(x, W, xb, xbT, Wt);
        attn_po<<<512, 512, 0, stream>>>(xb, xbT, O);
        ogemm<<<512, 256, 0, stream>>>(O, Wt, out);
    } else {
        // Fallback: round-0 proven pipeline.
        short* xb = (short*)d_ws;                              // 4 MiB
        short* ZT = (short*)d_ws + (size_t)B_ * T_ * C_;       // 64 MiB
        short* Wt = ZT + (size_t)B_ * H_ * 1024 * 1024;        // 32 MiB

        const bool big_ws = ws_size >= (size_t)100 * 1024 * 1024;
        cvt_x<<<(B_ * T_ * C_) / (256 * 8), 256, 0, stream>>>(x, xb);
        if (big_ws) {
            cvt_w<<<16 * 16 * 16, 256, 0, stream>>>(W, Wt);
            zgemm_fast<<<16 * 16 * 8, 256, 0, stream>>>(xb, Wt, ZT);
        } else {
            zgemm_sm<<<H_ * 8 * 8, 256, 0, stream>>>(xb, W, ZT);
        }
        attn<<<256, 512, 0, stream>>>(xb, ZT, out);
    }
}

// Round 13
// 316.476 us; speedup vs baseline: 1.2150x; 1.1674x over previous
//
#include <hip/hip_runtime.h>
#include <hip/hip_bf16.h>

#define B_ 2
#define T_ 1024
#define C_ 1024
#define H_ 16

typedef short bf16x8 __attribute__((ext_vector_type(8)));
typedef float f32x4 __attribute__((ext_vector_type(4)));

#define MFMA16(a, b, c) __builtin_amdgcn_mfma_f32_16x16x32_bf16(a, b, c, 0, 0, 0)

__device__ inline short f2bf(float x) {
    union { __hip_bfloat16 h; short s; } u;
    u.h = __float2bfloat16(x);
    return u.s;
}

__device__ inline void gl_lds16(const void* g, void* l) {
    __builtin_amdgcn_global_load_lds(
        (const __attribute__((address_space(1))) unsigned int*)g,
        (__attribute__((address_space(3))) unsigned int*)l, 16, 0, 0);
}

// ---------------------------------------------------------------------------
// Kernel: x (fp32) -> xb (bf16), flat. 2M elems, 8/thread. (fallback path)
// ---------------------------------------------------------------------------
__global__ __launch_bounds__(256) void cvt_x(const float* __restrict__ x,
                                             short* __restrict__ xb) {
    int idx = (blockIdx.x * 256 + threadIdx.x) * 8;
    float4 a = *(const float4*)(x + idx);
    float4 b = *(const float4*)(x + idx + 4);
    bf16x8 v;
    v[0] = f2bf(a.x); v[1] = f2bf(a.y); v[2] = f2bf(a.z); v[3] = f2bf(a.w);
    v[4] = f2bf(b.x); v[5] = f2bf(b.y); v[6] = f2bf(b.z); v[7] = f2bf(b.w);
    *(bf16x8*)(xb + idx) = v;
}

// ---------------------------------------------------------------------------
// Kernel: generic fp32->bf16 64x64 tile transpose (fallback path).
// ---------------------------------------------------------------------------
__global__ __launch_bounds__(256) void cvt_w(const float* __restrict__ W,
                                             short* __restrict__ Wt) {
    __shared__ float T[64][65];
    const int bid = blockIdx.x;
    const int nb = bid & 15, cb = (bid >> 4) & 15, h = bid >> 8;
    const int t = threadIdx.x;
    const int c0 = cb * 64, n0 = nb * 64;
    const float* src = W + (size_t)(h * 1024 + c0) * 1024 + n0;
    {
        const int cl = t >> 4, nl = (t & 15) * 4;
#pragma unroll
        for (int r = 0; r < 4; ++r) {
            float4 v = *(const float4*)(src + (size_t)(cl + r * 16) * 1024 + nl);
            T[cl + r * 16][nl + 0] = v.x;
            T[cl + r * 16][nl + 1] = v.y;
            T[cl + r * 16][nl + 2] = v.z;
            T[cl + r * 16][nl + 3] = v.w;
        }
    }
    __syncthreads();
    {
        short* dst = Wt + (size_t)(h * 1024 + n0) * 1024 + c0;
        const int nl = t >> 3, cl8 = (t & 7) * 8;
#pragma unroll
        for (int r = 0; r < 2; ++r) {
            const int n = nl + r * 32;
            bf16x8 o;
#pragma unroll
            for (int j = 0; j < 8; ++j) o[j] = f2bf(T[cl8 + j][n]);
            *(bf16x8*)(dst + (size_t)n * 1024 + cl8) = o;
        }
    }
}

// ---------------------------------------------------------------------------
// Kernel: cvt_fused — one launch replaces cvt_x + cvt_w(xbT) + cvt_w(Wt).
// Blocks 0..511:   xbT[b][ch][s] = bf16(x[b][s][ch])  AND  xb straight-thru.
// Blocks 512..4607: Wt[h][n][c] = bf16(W[h*1024+c][n])  (bid-512).
// ---------------------------------------------------------------------------
__global__ __launch_bounds__(256) void cvt_fused(const float* __restrict__ x,
                                                 const float* __restrict__ W,
                                                 short* __restrict__ xb,
                                                 short* __restrict__ xbT,
                                                 short* __restrict__ Wt) {
    __shared__ float T[64][65];
    const int bid0 = blockIdx.x;
    const bool isX = bid0 < 512;
    const int bid = isX ? bid0 : bid0 - 512;
    const float* srcb = isX ? x : W;
    short* dstb = isX ? xbT : Wt;
    const int nb = bid & 15, cb = (bid >> 4) & 15, g = bid >> 8;
    const int t = threadIdx.x;
    const int c0 = cb * 64, n0 = nb * 64;
    const float* src = srcb + (size_t)(g * 1024 + c0) * 1024 + n0;
    {
        const int cl = t >> 4, nl = (t & 15) * 4;
#pragma unroll
        for (int r = 0; r < 4; ++r) {
            float4 v = *(const float4*)(src + (size_t)(cl + r * 16) * 1024 + nl);
            T[cl + r * 16][nl + 0] = v.x;
            T[cl + r * 16][nl + 1] = v.y;
            T[cl + r * 16][nl + 2] = v.z;
            T[cl + r * 16][nl + 3] = v.w;
        }
    }
    __syncthreads();
    {
        short* dst = dstb + (size_t)(g * 1024 + n0) * 1024 + c0;
        const int nl = t >> 3, cl8 = (t & 7) * 8;
#pragma unroll
        for (int r = 0; r < 2; ++r) {
            const int n = nl + r * 32;
            bf16x8 o;
#pragma unroll
            for (int j = 0; j < 8; ++j) o[j] = f2bf(T[cl8 + j][n]);
            *(bf16x8*)(dst + (size_t)n * 1024 + cl8) = o;
        }
    }
    if (isX) {
        const int rl = t >> 3, c8 = (t & 7) * 8;
#pragma unroll
        for (int rr = 0; rr < 2; ++rr) {
            const int row = rl + rr * 32;
            bf16x8 o;
#pragma unroll
            for (int j = 0; j < 8; ++j) o[j] = f2bf(T[row][c8 + j]);
            *(bf16x8*)(xb + (size_t)(g * 1024 + c0 + row) * 1024 + n0 + c8) = o;
        }
    }
}

// ---------------------------------------------------------------------------
// Kernel: attn_po v3 (round-6/8/9/10 proven, ~155 us). UNCHANGED.
// ---------------------------------------------------------------------------
__global__ __launch_bounds__(512, 2) void attn_po(const short* __restrict__ xb,
                                                  const short* __restrict__ xbT,
                                                  short* __restrict__ O) {
    __shared__ short Pb[2][64][72];     // probs bf16, double-buffered
    __shared__ float row_al[2][64];
    __shared__ float row_l[64];
    __shared__ int   flags[2][4];

    const int tid = threadIdx.x;
    const int bh = blockIdx.x & 31;                  // XCD-pinned (b,h)
    const int rest = blockIdx.x >> 5;                // 0..15
    const int tb = (rest < 8) ? rest : 23 - rest;    // pair long+short tiles
    const int b = bh >> 4, h = bh & 15;
    const int lane = tid & 63, q = lane >> 4, l16 = lane & 15;
    const int w = tid >> 6;
    const int g = w & 3;          // QK row-group
    const int nw = w * 128;       // PV channel base
    const short* xbb = xb + ((size_t)b << 20);
    const short* vtb = xbT + ((size_t)b << 20);   // [c][s], s contiguous

    const int t0 = tb * 64;
    const int nch = tb + 1;

    f32x4 acc[4][8];
#pragma unroll
    for (int mt = 0; mt < 4; ++mt)
#pragma unroll
        for (int nt = 0; nt < 8; ++nt) acc[mt][nt] = (f32x4){0.f, 0.f, 0.f, 0.f};
    float m_r[4], l_r[4];
#pragma unroll
    for (int r = 0; r < 4; ++r) { m_r[r] = -3.0e38f; l_r[r] = 0.f; }

    bf16x8 qf[2];
    if (w < 4) {
#pragma unroll
        for (int ks = 0; ks < 2; ++ks)
            qf[ks] = *(const bf16x8*)(xbb + (size_t)(t0 + g * 16 + l16) * 1024 +
                                      h * 64 + ks * 32 + q * 8);
    }

    for (int ci = -1; ci < nch; ++ci) {
        __syncthreads();
        const int cc = ci + 1;
        if (w < 4 && cc < nch) {
            const int s0 = (cc == 0) ? t0 : (cc - 1) * 64;
            const int par = cc & 1;
            // QK^T
            f32x4 sf[4];
#pragma unroll
            for (int st = 0; st < 4; ++st) sf[st] = (f32x4){0.f, 0.f, 0.f, 0.f};
#pragma unroll
            for (int st = 0; st < 4; ++st)
#pragma unroll
                for (int ks = 0; ks < 2; ++ks) {
                    bf16x8 kf = *(const bf16x8*)(xbb +
                        (size_t)(s0 + st * 16 + l16) * 1024 + h * 64 + ks * 32 + q * 8);
                    sf[st] = MFMA16(qf[ks], kf, sf[st]);
                }
            // In-register online softmax (rows q*4+r of group g)
            float mx[4] = {-3.0e38f, -3.0e38f, -3.0e38f, -3.0e38f};
#pragma unroll
            for (int st = 0; st < 4; ++st)
#pragma unroll
                for (int r = 0; r < 4; ++r) {
                    float v = sf[st][r] * 0.25f;
                    if (cc == 0 && (s0 + st * 16 + l16) > (t0 + g * 16 + q * 4 + r))
                        v = -3.0e38f;
                    sf[st][r] = v;
                    mx[r] = fmaxf(mx[r], v);
                }
#pragma unroll
            for (int r = 0; r < 4; ++r) {
                mx[r] = fmaxf(mx[r], __shfl_xor(mx[r], 1));
                mx[r] = fmaxf(mx[r], __shfl_xor(mx[r], 2));
                mx[r] = fmaxf(mx[r], __shfl_xor(mx[r], 4));
                mx[r] = fmaxf(mx[r], __shfl_xor(mx[r], 8));
            }
            float sum[4], al[4];
            int upd = 0;
#pragma unroll
            for (int r = 0; r < 4; ++r) {
                float m_new = fmaxf(m_r[r], mx[r]);
                al[r] = __expf(m_r[r] - m_new);
                upd |= (m_new > m_r[r]) ? 1 : 0;
                m_r[r] = m_new;
                sum[r] = 0.f;
            }
#pragma unroll
            for (int st = 0; st < 4; ++st)
#pragma unroll
                for (int r = 0; r < 4; ++r) {
                    float pv = __expf(sf[st][r] - m_r[r]);
                    sum[r] += pv;
                    Pb[par][g * 16 + q * 4 + r][st * 16 + l16] = f2bf(pv);
                }
#pragma unroll
            for (int r = 0; r < 4; ++r) {
                sum[r] += __shfl_xor(sum[r], 1);
                sum[r] += __shfl_xor(sum[r], 2);
                sum[r] += __shfl_xor(sum[r], 4);
                sum[r] += __shfl_xor(sum[r], 8);
                l_r[r] = l_r[r] * al[r] + sum[r];
            }
            if (l16 == 0) {
#pragma unroll
                for (int r = 0; r < 4; ++r) row_al[par][g * 16 + q * 4 + r] = al[r];
            }
            int any_upd = __any(upd);
            if (lane == 0) flags[par][g] = any_upd;
        }
        if (ci >= 0) {
            const int par = ci & 1;
            // Rescale accumulators only if some row max moved.
            if (flags[par][0] | flags[par][1] | flags[par][2] | flags[par][3]) {
#pragma unroll
                for (int mt = 0; mt < 4; ++mt) {
                    float a0 = row_al[par][mt * 16 + q * 4 + 0];
                    float a1 = row_al[par][mt * 16 + q * 4 + 1];
                    float a2 = row_al[par][mt * 16 + q * 4 + 2];
                    float a3 = row_al[par][mt * 16 + q * 4 + 3];
#pragma unroll
                    for (int nt = 0; nt < 8; ++nt) {
                        acc[mt][nt][0] *= a0;
                        acc[mt][nt][1] *= a1;
                        acc[mt][nt][2] *= a2;
                        acc[mt][nt][3] *= a3;
                    }
                }
            }
            // PV: V-fragments from xbT (L2-hot), point-of-use.
            bf16x8 pf[4][2];
#pragma unroll
            for (int mt = 0; mt < 4; ++mt)
#pragma unroll
                for (int ks = 0; ks < 2; ++ks)
                    pf[mt][ks] = *(bf16x8*)&Pb[par][mt * 16 + l16][ks * 32 + q * 8];
            const int s0p = (ci == 0) ? t0 : (ci - 1) * 64;
#pragma unroll
            for (int nt = 0; nt < 8; ++nt)
#pragma unroll
                for (int ks = 0; ks < 2; ++ks) {
                    bf16x8 vf = *(const bf16x8*)(vtb +
                        (size_t)(nw + nt * 16 + l16) * 1024 + s0p + ks * 32 + q * 8);
#pragma unroll
                    for (int mt = 0; mt < 4; ++mt)
                        acc[mt][nt] = MFMA16(pf[mt][ks], vf, acc[mt][nt]);
                }
        }
    }

    // Epilogue: share row sums, normalize, PLAIN bf16 stores to O.
    if (w < 4 && l16 == 0) {
#pragma unroll
        for (int r = 0; r < 4; ++r) row_l[g * 16 + q * 4 + r] = l_r[r];
    }
    __syncthreads();
    short* ob = O + ((((size_t)(b * 1024 + t0) * 16) + h) << 10);
#pragma unroll
    for (int mt = 0; mt < 4; ++mt) {
        float i0 = 1.f / row_l[mt * 16 + q * 4 + 0];
        float i1 = 1.f / row_l[mt * 16 + q * 4 + 1];
        float i2 = 1.f / row_l[mt * 16 + q * 4 + 2];
        float i3 = 1.f / row_l[mt * 16 + q * 4 + 3];
#pragma unroll
        for (int nt = 0; nt < 8; ++nt) {
            size_t base = (size_t)(mt * 16 + q * 4) * 16384 + nw + nt * 16 + l16;
            ob[base]         = f2bf(acc[mt][nt][0] * i0);
            ob[base + 16384] = f2bf(acc[mt][nt][1] * i1);
            ob[base + 32768] = f2bf(acc[mt][nt][2] * i2);
            ob[base + 49152] = f2bf(acc[mt][nt][3] * i3);
        }
    }
}

// ---------------------------------------------------------------------------
// Kernel: ogemm v9 — out[m][n] += O[m][k] * Wt[k->(h,c)][n], 256x256 tile,
// row-cooperative PRE-SWIZZLED staging.
// Diagnosis (R8-R12): total staged bytes = K*2B*M*N*(1/BM+1/BN) = 1 GB at
// 128-tiles, moving at the measured ~11 B/cy/CU global-load ceiling with
// 16B-per-lane strided access (64 cache lines / wave-instruction). Fix:
//  * BM=BN=256 -> staged bytes 512 MB (halved).
//  * slot=(row,kg): lanes cover 8 consecutive rows x all 8 16B-chunks of
//    each 128B row -> 128B contiguous per row, 16 lines/instr (4x fewer).
//  * gl_lds16 dest is linear, so the chunk permutation kgg = kg^(row&7) is
//    applied on the GLOBAL side (m173 pattern) and the same XOR on ds_read:
//    per-16-lane group banks spread 8-way, 2-way alias = free (m136).
//    Without the XOR this layout would be a 16-way read conflict.
// Split-K 8, kq-per-XCD (R9 map, FETCH held ideal), grid 256, 512 thr,
// 8 waves 2m x 4n (128x64 each), acc[8][4]=128 VGPR, (512,1) cap 256.
// 2-barrier loop (proven; NO source pipelining). LDS 64 KB single-buffer.
// Epilogue: fp32 atomicAdd (out pre-zeroed), 16.8M atomics (R9 level).
// ---------------------------------------------------------------------------
__global__ __launch_bounds__(512, 1) void ogemm(const short* __restrict__ O,
                                                const short* __restrict__ Wt,
                                                float* __restrict__ out) {
    __shared__ short Al[256][8][8];   // [row][kgslot][8elem]  32 KiB
    __shared__ short Bl[256][8][8];   // [row][kgslot][8elem]  32 KiB

    const int orig = blockIdx.x;                   // 256 blocks; XCD = orig&7
    const int xc = orig & 7, j = orig >> 3;        // j in 0..31
    const int kq  = xc;                            // one kq per XCD (R9 map)
    const int m_t = j >> 2;                        // 0..7 (slow)
    const int n_t = j & 3;                         // 0..3 (fast)
    const int m0 = m_t * 256, n0 = n_t * 256;
    const int t = threadIdx.x;                     // 0..511
    const int lane = t & 63, q = lane >> 4, l16 = lane & 15;
    const int wv = t >> 6;                         // 0..7
    const int wm = (wv & 1) * 128, wn = (wv >> 1) * 64;

    const short* Ab = O + (size_t)m0 * 16384;

    // Staging slots: 4 per thread per operand. slot = t + s*512;
    // row = slot>>3 (8 consecutive rows per wave), kgl = slot&7 (LDS chunk),
    // kgg = kgl ^ (row&7) (global chunk — pre-swizzle).
    char* al0 = (char*)&Al[0][0][0] + (size_t)t * 16;
    char* bl0 = (char*)&Bl[0][0][0] + (size_t)t * 16;

    f32x4 acc[8][4];
#pragma unroll
    for (int i = 0; i < 8; ++i)
#pragma unroll
        for (int jj = 0; jj < 4; ++jj) acc[i][jj] = (f32x4){0.f, 0.f, 0.f, 0.f};

    const int kbase = kq * 2048;                   // 2048 K per split (8 way)
    for (int kk = 0; kk < 2048; kk += 64) {
        const int k0 = kbase + kk;
        const int h = k0 >> 10, c0 = k0 & 1023;    // BK=64 never straddles h
        const short* Bb = Wt + ((size_t)h << 20) + (size_t)n0 * 1024 + c0;
        __syncthreads();
#pragma unroll
        for (int s = 0; s < 4; ++s) {
            const int slot = t + s * 512;
            const int row = slot >> 3, kgl = slot & 7;
            const int kgg = kgl ^ (row & 7);
            gl_lds16(Ab + (size_t)row * 16384 + k0 + kgg * 8, al0 + s * 8192);
            gl_lds16(Bb + (size_t)row * 1024 + kgg * 8, bl0 + s * 8192);
        }
        __syncthreads();
#pragma unroll
        for (int ks = 0; ks < 2; ++ks) {
            const int kg = q + 4 * ks;
            bf16x8 af[8], bfr[4];
#pragma unroll
            for (int i = 0; i < 8; ++i) {
                const int ra = wm + i * 16 + l16;
                af[i] = *(bf16x8*)&Al[ra][kg ^ (ra & 7)][0];
            }
#pragma unroll
            for (int jj = 0; jj < 4; ++jj) {
                const int rb = wn + jj * 16 + l16;
                bfr[jj] = *(bf16x8*)&Bl[rb][kg ^ (rb & 7)][0];
            }
#pragma unroll
            for (int i = 0; i < 8; ++i)
#pragma unroll
                for (int jj = 0; jj < 4; ++jj)
                    acc[i][jj] = MFMA16(af[i], bfr[jj], acc[i][jj]);
        }
    }

    // Epilogue: out[m][n] atomic add (split-K partial).
#pragma unroll
    for (int i = 0; i < 8; ++i)
#pragma unroll
        for (int jj = 0; jj < 4; ++jj)
#pragma unroll
            for (int r = 0; r < 4; ++r) {
                int m = m0 + wm + i * 16 + q * 4 + r;
                int n = n0 + wn + jj * 16 + l16;
                atomicAdd(out + (size_t)m * 1024 + n, acc[i][jj][r]);
            }
}

// ---------------------------------------------------------------------------
// Fallback path kernels (round-0 proven): zgemm_fast/zgemm_sm + atomic attn.
// ---------------------------------------------------------------------------
__global__ __launch_bounds__(256, 4) void zgemm_fast(const short* __restrict__ xb,
                                                     const short* __restrict__ Wt,
                                                     short* __restrict__ ZT) {
    __shared__ short Al[4][128][8];
    __shared__ short Bl[4][128][8];

    const int bid = blockIdx.x;
    const int n_t = bid & 7, h = (bid >> 3) & 15, s_t = bid >> 7;
    const int n0 = n_t * 128, s0g = s_t * 128;
    const int t = threadIdx.x;
    const int lane = t & 63, q = lane >> 4, l16 = lane & 15;
    const int wv = t >> 6;
    const int wm = (wv & 1) * 64, wn = (wv >> 1) * 64;

    const short* Ab = Wt + ((size_t)h * 1024 + n0) * 1024;
    const short* Bb = xb + (size_t)s0g * 1024;
    const int srow = t & 127, skg = t >> 7;

    char* al_base = (char*)&Al[0][0][0] + (size_t)t * 16;
    char* bl_base = (char*)&Bl[0][0][0] + (size_t)t * 16;

    f32x4 acc[4][4];
#pragma unroll
    for (int i = 0; i < 4; ++i)
#pragma unroll
        for (int j = 0; j < 4; ++j) acc[i][j] = (f32x4){0.f, 0.f, 0.f, 0.f};

    for (int k0 = 0; k0 < 1024; k0 += 32) {
        __syncthreads();
        gl_lds16(Ab + (size_t)srow * 1024 + k0 + skg * 8, al_base);
        gl_lds16(Ab + (size_t)srow * 1024 + k0 + (skg + 2) * 8, al_base + 4096);
        gl_lds16(Bb + (size_t)srow * 1024 + k0 + skg * 8, bl_base);
        gl_lds16(Bb + (size_t)srow * 1024 + k0 + (skg + 2) * 8, bl_base + 4096);
        __syncthreads();
        bf16x8 af[4], bfr[4];
#pragma unroll
        for (int i = 0; i < 4; ++i) af[i] = *(bf16x8*)&Al[q][wm + i * 16 + l16][0];
#pragma unroll
        for (int j = 0; j < 4; ++j) bfr[j] = *(bf16x8*)&Bl[q][wn + j * 16 + l16][0];
#pragma unroll
        for (int i = 0; i < 4; ++i)
#pragma unroll
            for (int j = 0; j < 4; ++j)
                acc[i][j] = MFMA16(af[i], bfr[j], acc[i][j]);
    }

    const int b = s0g >> 10, s_in0 = s0g & 1023;
    short* zb = ZT + ((size_t)(b * 16 + h) << 20);
#pragma unroll
    for (int i = 0; i < 4; ++i)
#pragma unroll
        for (int j = 0; j < 4; ++j)
#pragma unroll
            for (int r = 0; r < 4; ++r) {
                int n = n0 + wm + i * 16 + q * 4 + r;
                int s = s_in0 + wn + j * 16 + l16;
                zb[(size_t)n * 1024 + s] = f2bf(acc[i][j][r]);
            }
}

#define ZPAD 40

__global__ __launch_bounds__(256, 2) void zgemm_sm(const short* __restrict__ xb,
                                                   const float* __restrict__ W,
                                                   short* __restrict__ ZT) {
    __shared__ short Wts[128 * ZPAD];
    __shared__ short Xs[2][128 * ZPAD];

    const int tid = threadIdx.x;
    const int bs = blockIdx.x & 7;
    const int bn = (blockIdx.x >> 3) & 7;
    const int h  = blockIdx.x >> 6;
    const int s0 = bs * 128, n0 = bn * 128;
    const int lane = tid & 63, q = lane >> 4, l16 = lane & 15;
    const int w = tid >> 6, bw = w >> 1, sh = w & 1;

    f32x4 acc[8][4];
#pragma unroll
    for (int i = 0; i < 8; ++i)
#pragma unroll
        for (int j = 0; j < 4; ++j) acc[i][j] = (f32x4){0.f, 0.f, 0.f, 0.f};

    for (int k0 = 0; k0 < 1024; k0 += 32) {
        __syncthreads();
#pragma unroll
        for (int r = 0; r < 2; ++r) {
            const int c2 = ((tid >> 5) << 1) + (r << 4);
            const float* w0p = W + (size_t)(h * 1024 + k0 + c2) * 1024 + n0;
            const float* w1p = w0p + 1024;
#pragma unroll
            for (int i = 0; i < 4; ++i) {
                const int n = (tid & 31) + (i << 5);
                float wa = w0p[n], wb = w1p[n];
                unsigned u = (unsigned)(unsigned short)f2bf(wa) |
                             ((unsigned)(unsigned short)f2bf(wb) << 16);
                *(unsigned*)&Wts[n * ZPAD + c2] = u;
            }
        }
#pragma unroll
        for (int i = 0; i < 4; ++i) {
            const int id = tid + (i << 8);
            const int b2 = id >> 9, s = (id >> 2) & 127, cg = id & 3;
            bf16x8 v = *(const bf16x8*)(xb + (size_t)b2 * (T_ * C_) +
                                        (size_t)(s0 + s) * 1024 + k0 + cg * 8);
            *(bf16x8*)&Xs[b2][s * ZPAD + cg * 8] = v;
        }
        __syncthreads();

        bf16x8 af[8], bfr[4];
#pragma unroll
        for (int nt = 0; nt < 8; ++nt)
            af[nt] = *(bf16x8*)&Wts[(nt * 16 + l16) * ZPAD + q * 8];
#pragma unroll
        for (int st = 0; st < 4; ++st)
            bfr[st] = *(bf16x8*)&Xs[bw][(sh * 64 + st * 16 + l16) * ZPAD + q * 8];
#pragma unroll
        for (int nt = 0; nt < 8; ++nt)
#pragma unroll
            for (int st = 0; st < 4; ++st)
                acc[nt][st] = MFMA16(af[nt], bfr[st], acc[nt][st]);
    }

    short* zb = ZT + (size_t)(bw * 16 + h) * (1024 * 1024);
#pragma unroll
    for (int nt = 0; nt < 8; ++nt)
#pragma unroll
        for (int st = 0; st < 4; ++st)
#pragma unroll
            for (int r = 0; r < 4; ++r) {
                int n_abs = n0 + nt * 16 + q * 4 + r;
                int s_abs = s0 + sh * 64 + st * 16 + l16;
                zb[(size_t)n_abs * 1024 + s_abs] = f2bf(acc[nt][st][r]);
            }
}

__global__ __launch_bounds__(512, 2) void attn(const short* __restrict__ xb,
                                               const short* __restrict__ ZT,
                                               float* __restrict__ out) {
    __shared__ short Pb[2][64][72];
    __shared__ float row_al[2][64];
    __shared__ float row_l[64];
    __shared__ int   flags[2][4];

    const int tid = threadIdx.x;
    const int bh = blockIdx.x & 31, p = blockIdx.x >> 5;
    const int b = bh >> 4, h = bh & 15;
    const int lane = tid & 63, q = lane >> 4, l16 = lane & 15;
    const int w = tid >> 6;
    const int g = w & 3;
    const int nw = w * 128;
    const short* xbb = xb + ((size_t)b << 20);
    const short* ztb = ZT + ((size_t)(b * 16 + h) << 20);

    const int tiles[2] = { p, 15 - p };
    for (int ti = 0; ti < 2; ++ti) {
        const int tb = tiles[ti];
        const int t0 = tb * 64;
        const int nch = tb + 1;

        f32x4 acc[4][8];
#pragma unroll
        for (int mt = 0; mt < 4; ++mt)
#pragma unroll
            for (int nt = 0; nt < 8; ++nt) acc[mt][nt] = (f32x4){0.f, 0.f, 0.f, 0.f};
        float m_r[4], l_r[4];
#pragma unroll
        for (int r = 0; r < 4; ++r) { m_r[r] = -3.0e38f; l_r[r] = 0.f; }

        bf16x8 qf[2];
        if (w < 4) {
#pragma unroll
            for (int ks = 0; ks < 2; ++ks)
                qf[ks] = *(const bf16x8*)(xbb + (size_t)(t0 + g * 16 + l16) * 1024 +
                                          h * 64 + ks * 32 + q * 8);
        }

        for (int ci = -1; ci < nch; ++ci) {
            __syncthreads();
            const int cc = ci + 1;
            if (w < 4 && cc < nch) {
                const int s0 = (cc == 0) ? t0 : (cc - 1) * 64;
                const int par = cc & 1;
                f32x4 sf[4];
#pragma unroll
                for (int st = 0; st < 4; ++st) sf[st] = (f32x4){0.f, 0.f, 0.f, 0.f};
#pragma unroll
                for (int st = 0; st < 4; ++st)
#pragma unroll
                    for (int ks = 0; ks < 2; ++ks) {
                        bf16x8 kf = *(const bf16x8*)(xbb +
                            (size_t)(s0 + st * 16 + l16) * 1024 + h * 64 + ks * 32 + q * 8);
                        sf[st] = MFMA16(qf[ks], kf, sf[st]);
                    }
                float mx[4] = {-3.0e38f, -3.0e38f, -3.0e38f, -3.0e38f};
#pragma unroll
                for (int st = 0; st < 4; ++st)
#pragma unroll
                    for (int r = 0; r < 4; ++r) {
                        float v = sf[st][r] * 0.25f;
                        if (cc == 0 && (s0 + st * 16 + l16) > (t0 + g * 16 + q * 4 + r))
                            v = -3.0e38f;
                        sf[st][r] = v;
                        mx[r] = fmaxf(mx[r], v);
                    }
#pragma unroll
                for (int r = 0; r < 4; ++r) {
                    mx[r] = fmaxf(mx[r], __shfl_xor(mx[r], 1));
                    mx[r] = fmaxf(mx[r], __shfl_xor(mx[r], 2));
                    mx[r] = fmaxf(mx[r], __shfl_xor(mx[r], 4));
                    mx[r] = fmaxf(mx[r], __shfl_xor(mx[r], 8));
                }
                float sum[4], al[4];
                int upd = 0;
#pragma unroll
                for (int r = 0; r < 4; ++r) {
                    float m_new = fmaxf(m_r[r], mx[r]);
                    al[r] = __expf(m_r[r] - m_new);
                    upd |= (m_new > m_r[r]) ? 1 : 0;
                    m_r[r] = m_new;
                    sum[r] = 0.f;
                }
#pragma unroll
                for (int st = 0; st < 4; ++st)
#pragma unroll
                    for (int r = 0; r < 4; ++r) {
                        float pv = __expf(sf[st][r] - m_r[r]);
                        sum[r] += pv;
                        Pb[par][g * 16 + q * 4 + r][st * 16 + l16] = f2bf(pv);
                    }
#pragma unroll
                for (int r = 0; r < 4; ++r) {
                    sum[r] += __shfl_xor(sum[r], 1);
                    sum[r] += __shfl_xor(sum[r], 2);
                    sum[r] += __shfl_xor(sum[r], 4);
                    sum[r] += __shfl_xor(sum[r], 8);
                    l_r[r] = l_r[r] * al[r] + sum[r];
                }
                if (l16 == 0) {
#pragma unroll
                    for (int r = 0; r < 4; ++r) row_al[par][g * 16 + q * 4 + r] = al[r];
                }
                int any_upd = __any(upd);
                if (lane == 0) flags[par][g] = any_upd;
            }
            if (ci >= 0) {
                const int par = ci & 1;
                if (flags[par][0] | flags[par][1] | flags[par][2] | flags[par][3]) {
#pragma unroll
                    for (int mt = 0; mt < 4; ++mt) {
                        float a0 = row_al[par][mt * 16 + q * 4 + 0];
                        float a1 = row_al[par][mt * 16 + q * 4 + 1];
                        float a2 = row_al[par][mt * 16 + q * 4 + 2];
                        float a3 = row_al[par][mt * 16 + q * 4 + 3];
#pragma unroll
                        for (int nt = 0; nt < 8; ++nt) {
                            acc[mt][nt][0] *= a0;
                            acc[mt][nt][1] *= a1;
                            acc[mt][nt][2] *= a2;
                            acc[mt][nt][3] *= a3;
                        }
                    }
                }
                bf16x8 pf[4][2];
#pragma unroll
                for (int mt = 0; mt < 4; ++mt)
#pragma unroll
                    for (int ks = 0; ks < 2; ++ks)
                        pf[mt][ks] = *(bf16x8*)&Pb[par][mt * 16 + l16][ks * 32 + q * 8];
                const int s0p = (ci == 0) ? t0 : (ci - 1) * 64;
#pragma unroll
                for (int nt = 0; nt < 8; ++nt)
#pragma unroll
                    for (int ks = 0; ks < 2; ++ks) {
                        bf16x8 vf = *(const bf16x8*)(ztb +
                            (size_t)(nw + nt * 16 + l16) * 1024 + s0p + ks * 32 + q * 8);
#pragma unroll
                        for (int mt = 0; mt < 4; ++mt)
                            acc[mt][nt] = MFMA16(pf[mt][ks], vf, acc[mt][nt]);
                    }
            }
        }

        if (w < 4 && l16 == 0) {
#pragma unroll
            for (int r = 0; r < 4; ++r) row_l[g * 16 + q * 4 + r] = l_r[r];
        }
        __syncthreads();
#pragma unroll
        for (int mt = 0; mt < 4; ++mt) {
            float i0 = 1.f / row_l[mt * 16 + q * 4 + 0];
            float i1 = 1.f / row_l[mt * 16 + q * 4 + 1];
            float i2 = 1.f / row_l[mt * 16 + q * 4 + 2];
            float i3 = 1.f / row_l[mt * 16 + q * 4 + 3];
#pragma unroll
            for (int nt = 0; nt < 8; ++nt) {
                size_t base = (size_t)(b * 1024 + t0 + mt * 16 + q * 4) * 1024 +
                              nw + nt * 16 + l16;
                atomicAdd(out + base,            acc[mt][nt][0] * i0);
                atomicAdd(out + base + 1024,     acc[mt][nt][1] * i1);
                atomicAdd(out + base + 2048,     acc[mt][nt][2] * i2);
                atomicAdd(out + base + 3072,     acc[mt][nt][3] * i3);
            }
        }
        __syncthreads();
    }
}

// ---------------------------------------------------------------------------
extern "C" void kernel_launch(void* const* d_in, const int* in_sizes, int n_in,
                              void* d_out, int out_size, void* d_ws, size_t ws_size,
                              hipStream_t stream) {
    const float* x = (const float*)d_in[0];
    // d_in[1] (mask) recomputed analytically.
    const float* W = (const float*)d_in[2];
    float* out = (float*)d_out;

    hipMemsetAsync(d_out, 0, (size_t)B_ * T_ * C_ * sizeof(float), stream);

    if (ws_size >= (size_t)104 * 1024 * 1024) {
        // O = P@x per head (plain stores), then one long-K GEMM.
        // ws layout (shorts): xb[0,2M) xbT[2M,4M) Wt[4M,20M) O[20M,52M)
        short* xb  = (short*)d_ws;
        short* xbT = xb + (size_t)2 * 1024 * 1024;
        short* Wt  = xb + (size_t)4 * 1024 * 1024;
        short* O   = xb + (size_t)20 * 1024 * 1024;

        cvt_fused<<<512 + 4096, 256, 0, stream>>>(x, W, xb, xbT, Wt);
        attn_po<<<512, 512, 0, stream>>>(xb, xbT, O);
        ogemm<<<256, 512, 0, stream>>>(O, Wt, out);
    } else {
        // Fallback: round-0 proven pipeline.
        short* xb = (short*)d_ws;                              // 4 MiB
        short* ZT = (short*)d_ws + (size_t)B_ * T_ * C_;       // 64 MiB
        short* Wt = ZT + (size_t)B_ * H_ * 1024 * 1024;        // 32 MiB

        const bool big_ws = ws_size >= (size_t)100 * 1024 * 1024;
        cvt_x<<<(B_ * T_ * C_) / (256 * 8), 256, 0, stream>>>(x, xb);
        if (big_ws) {
            cvt_w<<<16 * 16 * 16, 256, 0, stream>>>(W, Wt);
            zgemm_fast<<<16 * 16 * 8, 256, 0, stream>>>(xb, Wt, ZT);
        } else {
            zgemm_sm<<<H_ * 8 * 8, 256, 0, stream>>>(xb, W, ZT);
        }
        attn<<<256, 512, 0, stream>>>(xb, ZT, out);
    }
}